// Round 1
// baseline (2145.901 us; speedup 1.0000x reference)
//
#include <hip/hip_runtime.h>
#include <stdint.h>

typedef float f32x4 __attribute__((ext_vector_type(4)));
typedef __bf16 bf16x8 __attribute__((ext_vector_type(8)));
typedef unsigned short us4 __attribute__((ext_vector_type(4)));

#define GLD_LDS16(gp, lp) __builtin_amdgcn_global_load_lds( \
    (const __attribute__((address_space(1))) void*)(gp),    \
    (__attribute__((address_space(3))) void*)(lp), 16, 0, 0)

// ---------------- bf16 helpers (bit-level, RNE) ----------------
__device__ __forceinline__ unsigned short f2bf(float f) {
  uint32_t u = __float_as_uint(f);
  uint32_t r = (u + 0x7FFFu + ((u >> 16) & 1u)) >> 16;
  return (unsigned short)r;
}
__device__ __forceinline__ float bf2f(unsigned short h) {
  return __uint_as_float(((uint32_t)h) << 16);
}

// ---------------- GEMM: C[M][ldc] = A[M][K] * B[Npad][K]^T (+bias) ----------------
// A, B are bf16 bit-patterns (ushort). 128x128 tile, BK=32, 4 waves (2x2),
// each wave 64x64 = 4x4 fragments of 16x16x32 MFMA. m97 structure.
#define BM 128
#define BN 128
#define BK 32

__global__ __launch_bounds__(256) void gemm_bt(
    const unsigned short* __restrict__ A,
    const unsigned short* __restrict__ B,
    float* __restrict__ C,
    const float* __restrict__ bias,
    int M, int K, int ldc, int Nreal, int nbn, int accumulate)
{
  __shared__ unsigned short As[BM * BK];
  __shared__ unsigned short Bs[BN * BK];

  const int tid  = threadIdx.x;
  const int wave = tid >> 6;
  const int lane = tid & 63;

  // XCD-aware bijective swizzle (nwg % 8 == 0 guaranteed by launch)
  const int nwg = gridDim.x;
  const int cpx = nwg >> 3;
  const int b   = blockIdx.x;
  const int swz = (b & 7) * cpx + (b >> 3);
  const int bm  = swz / nbn;
  const int bn  = swz - bm * nbn;

  const int rowA = bm * BM;
  const int rowB = bn * BN;

  const int wm = wave >> 1;  // 0..1
  const int wn = wave & 1;   // 0..1

  // staging: thread t loads 16B: row (t>>2) [+64 for 2nd call], chunk (t&3)
  const unsigned short* aSrc = A + (size_t)(rowA + (tid >> 2)) * K + (tid & 3) * 8;
  const unsigned short* bSrc = B + (size_t)(rowB + (tid >> 2)) * K + (tid & 3) * 8;
  unsigned short* aDst = As + wave * 512;  // wave-uniform; HW adds lane*16B
  unsigned short* bDst = Bs + wave * 512;

  const int lrow = lane & 15;
  const int lko  = (lane >> 4) * 8;

  f32x4 acc[4][4] = {};

  for (int k0 = 0; k0 < K; k0 += BK) {
    GLD_LDS16(aSrc + k0,                   aDst);
    GLD_LDS16(aSrc + k0 + (size_t)64 * K,  aDst + 2048);
    GLD_LDS16(bSrc + k0,                   bDst);
    GLD_LDS16(bSrc + k0 + (size_t)64 * K,  bDst + 2048);
    __syncthreads();  // compiler drains vmcnt before s_barrier

    bf16x8 af[4], bfr[4];
#pragma unroll
    for (int m = 0; m < 4; ++m)
      af[m] = *(const bf16x8*)(As + (wm * 64 + m * 16 + lrow) * BK + lko);
#pragma unroll
    for (int n = 0; n < 4; ++n)
      bfr[n] = *(const bf16x8*)(Bs + (wn * 64 + n * 16 + lrow) * BK + lko);

#pragma unroll
    for (int m = 0; m < 4; ++m)
#pragma unroll
      for (int n = 0; n < 4; ++n)
        acc[m][n] = __builtin_amdgcn_mfma_f32_16x16x32_bf16(af[m], bfr[n], acc[m][n], 0, 0, 0);
    __syncthreads();
  }

  // C/D layout: col = lane&15, row = (lane>>4)*4 + reg
  const int ch = lane >> 4;
  const int cl = lane & 15;
#pragma unroll
  for (int n = 0; n < 4; ++n) {
    const int c = rowB + wn * 64 + n * 16 + cl;
    if (c >= Nreal) continue;
    const float bv = bias ? bias[c] : 0.0f;
#pragma unroll
    for (int m = 0; m < 4; ++m) {
#pragma unroll
      for (int j = 0; j < 4; ++j) {
        const int r = rowA + wm * 64 + m * 16 + ch * 4 + j;
        float* p = C + (size_t)r * ldc + c;
        float v = acc[m][n][j] + bv;
        if (accumulate) v += *p;
        *p = v;
      }
    }
  }
}

// ---------------- elementwise: binarize fp32 -> bf16 +-1 ----------------
__global__ void k_binarize(const float* __restrict__ in, unsigned short* __restrict__ out, size_t n4) {
  size_t i = (size_t)blockIdx.x * blockDim.x + threadIdx.x;
  const size_t stride = (size_t)gridDim.x * blockDim.x;
  for (; i < n4; i += stride) {
    float4 v = ((const float4*)in)[i];
    us4 o;
    o.x = (v.x >= 0.f) ? 0x3F80 : 0xBF80;
    o.y = (v.y >= 0.f) ? 0x3F80 : 0xBF80;
    o.z = (v.z >= 0.f) ? 0x3F80 : 0xBF80;
    o.w = (v.w >= 0.f) ? 0x3F80 : 0xBF80;
    ((us4*)out)[i] = o;
  }
}

// ---------------- column stats: exact integer sums in double ----------------
__global__ void k_colstats(const float* __restrict__ Z, double* __restrict__ sums, int H, int rows) {
  const int col = blockIdx.x * blockDim.x + threadIdx.x;
  const int r0  = blockIdx.y * rows;
  const float* p = Z + (size_t)r0 * H + col;
  double s = 0.0, ss = 0.0;
  for (int r = 0; r < rows; ++r) {
    float v = p[(size_t)r * H];
    s += (double)v;
    ss += (double)v * (double)v;
  }
  atomicAdd(&sums[col], s);
  atomicAdd(&sums[H + col], ss);
}

__global__ void k_bnfinal(const double* __restrict__ sums, const float* __restrict__ g,
                          const float* __restrict__ be, float2* __restrict__ coef,
                          int H, double invB) {
  const int j = blockIdx.x * blockDim.x + threadIdx.x;
  if (j >= H) return;
  const double mu  = sums[j] * invB;
  const double var = sums[H + j] * invB - mu * mu;
  const float rstd = (float)(1.0 / sqrt(var + 1e-5));
  const float sc = g[j] * rstd;
  const float sh = be[j] - (float)mu * sc;
  coef[j] = make_float2(sc, sh);
}

// ---------------- BN + sign -> bf16 +-1 ----------------
__global__ void k_bnsign(const float* __restrict__ Z, const float2* __restrict__ coef,
                         unsigned short* __restrict__ out, size_t n4, int Hmask) {
  size_t i = (size_t)blockIdx.x * blockDim.x + threadIdx.x;
  const size_t stride = (size_t)gridDim.x * blockDim.x;
  for (; i < n4; i += stride) {
    float4 z = ((const float4*)Z)[i];
    const int c0 = (int)((i << 2) & (size_t)Hmask);
    float2 q0 = coef[c0], q1 = coef[c0 + 1], q2 = coef[c0 + 2], q3 = coef[c0 + 3];
    us4 o;
    o.x = (z.x * q0.x + q0.y >= 0.f) ? 0x3F80 : 0xBF80;
    o.y = (z.y * q1.x + q1.y >= 0.f) ? 0x3F80 : 0xBF80;
    o.z = (z.z * q2.x + q2.y >= 0.f) ? 0x3F80 : 0xBF80;
    o.w = (z.w * q3.x + q3.y >= 0.f) ? 0x3F80 : 0xBF80;
    ((us4*)out)[i] = o;
  }
}

// ---------------- BN + clip -> split bf16 hi/lo ----------------
__global__ void k_bnclipsplit(const float* __restrict__ Z, const float2* __restrict__ coef,
                              unsigned short* __restrict__ hi, unsigned short* __restrict__ lo,
                              size_t n4, int Hmask) {
  size_t i = (size_t)blockIdx.x * blockDim.x + threadIdx.x;
  const size_t stride = (size_t)gridDim.x * blockDim.x;
  for (; i < n4; i += stride) {
    float4 z = ((const float4*)Z)[i];
    const int c0 = (int)((i << 2) & (size_t)Hmask);
    us4 oh, ol;
    float zz[4] = {z.x, z.y, z.z, z.w};
    unsigned short hh[4], ll[4];
#pragma unroll
    for (int t = 0; t < 4; ++t) {
      float2 q = coef[c0 + t];
      float v = zz[t] * q.x + q.y;
      v = fminf(1.f, fmaxf(-1.f, v));
      unsigned short h = f2bf(v);
      hh[t] = h;
      ll[t] = f2bf(v - bf2f(h));
    }
    oh.x = hh[0]; oh.y = hh[1]; oh.z = hh[2]; oh.w = hh[3];
    ol.x = ll[0]; ol.y = ll[1]; ol.z = ll[2]; ol.w = ll[3];
    ((us4*)hi)[i] = oh;
    ((us4*)lo)[i] = ol;
  }
}

// ---------------- split W4 (padded rows -> zeros) ----------------
__global__ void k_w4split(const float* __restrict__ W4, unsigned short* __restrict__ hi,
                          unsigned short* __restrict__ lo, int Nreal, int K, size_t n4) {
  size_t i = (size_t)blockIdx.x * blockDim.x + threadIdx.x;
  const size_t stride = (size_t)gridDim.x * blockDim.x;
  for (; i < n4; i += stride) {
    const size_t e0 = i << 2;
    const int row = (int)(e0 >> 12);  // K = 4096
    us4 oh, ol;
    if (row < Nreal) {
      float4 v = ((const float4*)W4)[i];
      float vv[4] = {v.x, v.y, v.z, v.w};
      unsigned short hh[4], ll[4];
#pragma unroll
      for (int t = 0; t < 4; ++t) {
        unsigned short h = f2bf(vv[t]);
        hh[t] = h;
        ll[t] = f2bf(vv[t] - bf2f(h));
      }
      oh.x = hh[0]; oh.y = hh[1]; oh.z = hh[2]; oh.w = hh[3];
      ol.x = ll[0]; ol.y = ll[1]; ol.z = ll[2]; ol.w = ll[3];
    } else {
      oh = (us4)0; ol = (us4)0;
    }
    ((us4*)hi)[i] = oh;
    ((us4*)lo)[i] = ol;
  }
}

// ---------------- launcher ----------------
extern "C" void kernel_launch(void* const* d_in, const int* in_sizes, int n_in,
                              void* d_out, int out_size, void* d_ws, size_t ws_size,
                              hipStream_t stream) {
  (void)in_sizes; (void)n_in; (void)out_size; (void)ws_size;
  const int Bt = 8192, K = 4096, H = 4096, NC = 1000, NCp = 1024;

  const float* x   = (const float*)d_in[0];
  const float* W1  = (const float*)d_in[2];
  const float* g1  = (const float*)d_in[4];
  const float* be1 = (const float*)d_in[5];
  const float* W2  = (const float*)d_in[6];
  const float* g2  = (const float*)d_in[8];
  const float* be2 = (const float*)d_in[9];
  const float* W3  = (const float*)d_in[10];
  const float* g3  = (const float*)d_in[12];
  const float* be3 = (const float*)d_in[13];
  const float* W4  = (const float*)d_in[14];
  const float* b4  = (const float*)d_in[15];
  float* out = (float*)d_out;

  char* ws = (char*)d_ws;
  unsigned short* Ab   = (unsigned short*)(ws);                      // 64MB: bf16 activations / A_hi
  unsigned short* Wb   = (unsigned short*)(ws + ((size_t)64 << 20)); // 32MB: binarized weights; reused for W4hi/lo
  float*          Z    = (float*)         (ws + ((size_t)96 << 20)); // 128MB: pre-BN GEMM output
  unsigned short* Alo  = (unsigned short*)(ws + ((size_t)224 << 20));// 64MB: A_lo
  double*         sums = (double*)        (ws + ((size_t)288 << 20));// 64KB
  float2*         coef = (float2*)        (ws + ((size_t)288 << 20) + 2 * H * sizeof(double));
  unsigned short* W4hi = Wb;                                         // 8MB (reuse after layer-3 GEMM)
  unsigned short* W4lo = Wb + (size_t)NCp * K;                       // 8MB

  const dim3 blk(256);
  auto gemm = [&](const unsigned short* Aop, const unsigned short* Bop, float* Cop,
                  const float* bias, int M, int Npad, int ldc, int Nreal, int accum) {
    const int nbm = M / BM, nbn = Npad / BN;
    gemm_bt<<<dim3(nbm * nbn), blk, 0, stream>>>(Aop, Bop, Cop, bias, M, K, ldc, Nreal, nbn, accum);
  };

  const size_t nX4 = (size_t)Bt * K / 4;  // activation float4 groups
  const size_t nW4 = (size_t)H * K / 4;   // weight float4 groups

  // binarize input
  k_binarize<<<2048, blk, 0, stream>>>(x, Ab, nX4);

  const float* Ws[3]  = {W1, W2, W3};
  const float* gs[3]  = {g1, g2, g3};
  const float* bes[3] = {be1, be2, be3};

  for (int layer = 0; layer < 3; ++layer) {
    k_binarize<<<2048, blk, 0, stream>>>(Ws[layer], Wb, nW4);
    gemm(Ab, Wb, Z, nullptr, Bt, H, H, H, 0);   // binarized bias is BN-invariant: skip
    hipMemsetAsync(sums, 0, 2 * H * sizeof(double), stream);
    k_colstats<<<dim3(H / 256, 32), blk, 0, stream>>>(Z, sums, H, Bt / 32);
    k_bnfinal<<<H / 256, blk, 0, stream>>>(sums, gs[layer], bes[layer], coef, H, 1.0 / Bt);
    if (layer < 2) {
      k_bnsign<<<2048, blk, 0, stream>>>(Z, coef, Ab, nX4, H - 1);
    } else {
      k_bnclipsplit<<<2048, blk, 0, stream>>>(Z, coef, Ab, Alo, nX4, H - 1);
    }
  }

  // final fp32-accurate layer via bf16 hi/lo split: C = Ah*Wh + Al*Wh + Ah*Wl + b4
  k_w4split<<<2048, blk, 0, stream>>>(W4, W4hi, W4lo, NC, K, (size_t)NCp * K / 4);
  gemm(Ab,  W4hi, out, b4,      Bt, NCp, NC, NC, 0);
  gemm(Alo, W4hi, out, nullptr, Bt, NCp, NC, NC, 1);
  gemm(Ab,  W4lo, out, nullptr, Bt, NCp, NC, NC, 1);
}

// Round 2
// 1895.662 us; speedup vs baseline: 1.1320x; 1.1320x over previous
//
#include <hip/hip_runtime.h>
#include <stdint.h>

typedef float f32x4 __attribute__((ext_vector_type(4)));
typedef __bf16 bf16x8 __attribute__((ext_vector_type(8)));
typedef unsigned short us4 __attribute__((ext_vector_type(4)));

#define GLD_LDS16(gp, lp) __builtin_amdgcn_global_load_lds( \
    (const __attribute__((address_space(1))) void*)(gp),    \
    (__attribute__((address_space(3))) void*)(lp), 16, 0, 0)

// ---------------- bf16 helpers (bit-level, RNE) ----------------
__device__ __forceinline__ unsigned short f2bf(float f) {
  uint32_t u = __float_as_uint(f);
  uint32_t r = (u + 0x7FFFu + ((u >> 16) & 1u)) >> 16;
  return (unsigned short)r;
}
__device__ __forceinline__ float bf2f(unsigned short h) {
  return __uint_as_float(((uint32_t)h) << 16);
}

// =====================================================================
// 256x256 8-phase GEMM (T1+T2+T3+T4+T5): C[M][ldc] = A[M][K] * B[N][K]^T
// 512 threads = 8 waves (2M x 4N). BK=64. LDS 128KiB (2 dbuf x (A,B) x 256x64 bf16).
// Per wave: 128x64 output = acc[8][4] f32x4. 16 MFMA/phase, 8 phases/iter,
// 2 K-tiles/iter. Stage 1 half-tile (2 x global_load_lds dwordx4) per phase.
// vmcnt(4) at phases 4 and 8 (derived deadline: 2 half-tiles in flight).
// LDS read swizzle: granule ^= (row&7); gload_lds dest linear, global src
// pre-swizzled (rule 21: both-sides-or-neither).
// =====================================================================

#define READ_A(BUF, MH)                                                        \
  do {                                                                         \
    _Pragma("unroll") for (int mp = 0; mp < 4; ++mp)                           \
      _Pragma("unroll") for (int kk = 0; kk < 2; ++kk)                         \
        a[mp][kk] = *(const bf16x8*)(asC + (BUF) * 32768 + (MH) * 16384 +      \
                                     rowOffA[mp] + gsw[kk]);                   \
  } while (0)

#define READ_B(BUF, NH)                                                        \
  do {                                                                         \
    _Pragma("unroll") for (int np = 0; np < 2; ++np)                           \
      _Pragma("unroll") for (int kk = 0; kk < 2; ++kk)                         \
        bb[np][kk] = *(const bf16x8*)(bsC + (BUF) * 32768 + (NH) * 16384 +     \
                                      rowOffB[np] + gsw[kk]);                  \
  } while (0)

#define STAGE_A(BUF, MH, T)                                                    \
  do {                                                                         \
    int tt = (T); if (tt >= nt) tt -= nt;                                      \
    const size_t ko = (size_t)tt * 64;                                         \
    GLD_LDS16(aStage0 + (size_t)(MH) * 64 * K + ko,                            \
              &As[BUF][(MH) * 8192 + wvOff]);                                  \
    GLD_LDS16(aStage0 + (size_t)(MH) * 64 * K + (size_t)128 * K + ko,          \
              &As[BUF][(MH) * 8192 + 4096 + wvOff]);                           \
  } while (0)

#define STAGE_B(BUF, NH, T)                                                    \
  do {                                                                         \
    int tt = (T); if (tt >= nt) tt -= nt;                                      \
    const size_t ko = (size_t)tt * 64;                                         \
    GLD_LDS16(bStage0 + (size_t)(NH) * 32 * K + ko,                            \
              &Bs[BUF][(NH) * 8192 + wvOff]);                                  \
    GLD_LDS16(bStage0 + (size_t)(NH) * 32 * K + (size_t)128 * K + ko,          \
              &Bs[BUF][(NH) * 8192 + 4096 + wvOff]);                           \
  } while (0)

#define MFMA_Q(MH, NH)                                                         \
  do {                                                                         \
    _Pragma("unroll") for (int mp = 0; mp < 4; ++mp)                           \
      _Pragma("unroll") for (int np = 0; np < 2; ++np)                         \
        _Pragma("unroll") for (int kk = 0; kk < 2; ++kk)                       \
          acc[(MH) * 4 + mp][(NH) * 2 + np] =                                  \
              __builtin_amdgcn_mfma_f32_16x16x32_bf16(                         \
                  a[mp][kk], bb[np][kk], acc[(MH) * 4 + mp][(NH) * 2 + np],    \
                  0, 0, 0);                                                    \
  } while (0)

#define PHASE(RA, RB, BUF, MH, NH, STAGE_STMT, DO_VM)                          \
  do {                                                                         \
    if (RA) READ_A(BUF, MH);                                                   \
    if (RB) READ_B(BUF, NH);                                                   \
    STAGE_STMT;                                                                \
    __builtin_amdgcn_s_barrier();                                              \
    asm volatile("s_waitcnt lgkmcnt(0)" ::: "memory");                         \
    __builtin_amdgcn_sched_barrier(0);                                         \
    __builtin_amdgcn_s_setprio(1);                                             \
    MFMA_Q(MH, NH);                                                            \
    __builtin_amdgcn_s_setprio(0);                                             \
    if (DO_VM) asm volatile("s_waitcnt vmcnt(4)" ::: "memory");                \
    __builtin_amdgcn_s_barrier();                                              \
    asm volatile("" ::: "memory");                                             \
  } while (0)

__global__ __launch_bounds__(512, 2) void gemm256(
    const unsigned short* __restrict__ A,
    const unsigned short* __restrict__ B,
    float* __restrict__ C,
    const float* __restrict__ bias,
    int M, int K, int ldc, int Nreal, int nbn, int accumulate)
{
  __shared__ unsigned short As[2][16384];  // [buf][256*64] bf16, 64KB
  __shared__ unsigned short Bs[2][16384];  // 64KB

  const int tid  = threadIdx.x;
  const int wave = tid >> 6;
  const int lane = tid & 63;
  const int wm   = wave >> 2;  // 0..1 (M)
  const int wn   = wave & 3;   // 0..3 (N)

  // XCD-aware bijective swizzle (nwg % 8 == 0 by construction)
  const int nwg = gridDim.x;
  const int cpx = nwg >> 3;
  const int bsw = (blockIdx.x & 7) * cpx + (blockIdx.x >> 3);
  const int bm  = bsw / nbn;
  const int bn  = bsw - bm * nbn;
  const int rowA = bm * 256;
  const int rowB = bn * 256;

  const int nt = K >> 6;  // K-tiles of 64

  // ---- staging addresses (pre-swizzled global source, linear LDS dest) ----
  const int trow = tid >> 3;                       // 0..63
  const int gl   = (tid & 7) ^ (trow & 7);         // swizzled granule
  const unsigned short* aStage0 = A + (size_t)(rowA + trow) * K + gl * 8;
  const unsigned short* bStage0 =
      B + (size_t)(rowB + ((trow >> 5) << 6) + (trow & 31)) * K + gl * 8;
  const int wvOff = wave * 512;  // elements; 8 rows x 64 per wave per call

  // ---- read addresses (swizzled) ----
  const char* asC = (const char*)&As[0][0];
  const char* bsC = (const char*)&Bs[0][0];
  int rowOffA[4], rowOffB[2], gsw[2];
#pragma unroll
  for (int mp = 0; mp < 4; ++mp)
    rowOffA[mp] = (wm * 64 + mp * 16 + (lane & 15)) * 128;
#pragma unroll
  for (int np = 0; np < 2; ++np)
    rowOffB[np] = (wn * 32 + np * 16 + (lane & 15)) * 128;
#pragma unroll
  for (int kk = 0; kk < 2; ++kk)
    gsw[kk] = ((((kk << 2) | (lane >> 4)) ^ (lane & 7)) << 4);

  bf16x8 a[4][2], bb[2][2];
  f32x4 acc[8][4] = {};

  // ---- prologue: tile0 (all 4 halves -> buf0), tile1 A0+B1 -> buf1 ----
  STAGE_A(0, 0, 0); STAGE_B(0, 1, 0); STAGE_A(0, 1, 0); STAGE_B(0, 0, 0);
  STAGE_A(1, 0, 1); STAGE_B(1, 1, 1);
  asm volatile("s_waitcnt vmcnt(4)" ::: "memory");
  __builtin_amdgcn_s_barrier();
  asm volatile("" ::: "memory");

  // ---- main loop: iteration computes tiles 2i (buf0) and 2i+1 (buf1) ----
  const int ni = nt >> 1;
  for (int i = 0; i < ni; ++i) {
    const int t1 = 2 * i + 1, t2 = 2 * i + 2, t3 = 2 * i + 3;
    PHASE(1, 1, 0, 0, 0, STAGE_A(1, 1, t1), 0);  // P1: read A-M0+B-N0; stage buf1.A1<-t1
    PHASE(0, 1, 0, 0, 1, STAGE_B(1, 0, t1), 0);  // P2: read B-N1;      stage buf1.B0<-t1
    PHASE(1, 0, 0, 1, 1, STAGE_A(0, 0, t2), 0);  // P3: read A-M1;      stage buf0.A0<-t2
    PHASE(0, 1, 0, 1, 0, STAGE_B(0, 1, t2), 1);  // P4: read B-N0;      stage buf0.B1<-t2; vmcnt
    PHASE(1, 1, 1, 0, 0, STAGE_A(0, 1, t2), 0);  // P5
    PHASE(0, 1, 1, 0, 1, STAGE_B(0, 0, t2), 0);  // P6
    PHASE(1, 0, 1, 1, 1, STAGE_A(1, 0, t3), 0);  // P7
    PHASE(0, 1, 1, 1, 0, STAGE_B(1, 1, t3), 1);  // P8: vmcnt
  }

  // ---- epilogue: C write. D layout: col=lane&15, row=(lane>>4)*4+j ----
  const int cl = lane & 15;
  const int ch = (lane >> 4) * 4;
#pragma unroll
  for (int nh = 0; nh < 2; ++nh) {
#pragma unroll
    for (int np = 0; np < 2; ++np) {
      const int c = rowB + wn * 64 + nh * 32 + np * 16 + cl;
      if (c >= Nreal) continue;
      const float bv = bias ? bias[c] : 0.0f;
#pragma unroll
      for (int mh = 0; mh < 2; ++mh) {
#pragma unroll
        for (int mp = 0; mp < 4; ++mp) {
          const int r = rowA + wm * 128 + mh * 64 + mp * 16 + ch;
          float* p = C + (size_t)r * ldc + c;
#pragma unroll
          for (int j = 0; j < 4; ++j) {
            float v = acc[mh * 4 + mp][nh * 2 + np][j] + bv;
            if (accumulate) v += p[(size_t)j * ldc];
            p[(size_t)j * ldc] = v;
          }
        }
      }
    }
  }
}

// =====================================================================
// 128x128 GEMM (m97 structure) — kept for the N=1024 final-layer passes
// =====================================================================
#define BM 128
#define BN 128
#define BK 32

__global__ __launch_bounds__(256) void gemm_bt(
    const unsigned short* __restrict__ A,
    const unsigned short* __restrict__ B,
    float* __restrict__ C,
    const float* __restrict__ bias,
    int M, int K, int ldc, int Nreal, int nbn, int accumulate)
{
  __shared__ unsigned short As[BM * BK];
  __shared__ unsigned short Bs[BN * BK];

  const int tid  = threadIdx.x;
  const int wave = tid >> 6;
  const int lane = tid & 63;

  const int nwg = gridDim.x;
  const int cpx = nwg >> 3;
  const int b   = blockIdx.x;
  const int swz = (b & 7) * cpx + (b >> 3);
  const int bm  = swz / nbn;
  const int bn  = swz - bm * nbn;

  const int rowA = bm * BM;
  const int rowB = bn * BN;

  const int wm = wave >> 1;
  const int wn = wave & 1;

  const unsigned short* aSrc = A + (size_t)(rowA + (tid >> 2)) * K + (tid & 3) * 8;
  const unsigned short* bSrc = B + (size_t)(rowB + (tid >> 2)) * K + (tid & 3) * 8;
  unsigned short* aDst = As + wave * 512;
  unsigned short* bDst = Bs + wave * 512;

  const int lrow = lane & 15;
  const int lko  = (lane >> 4) * 8;

  f32x4 acc[4][4] = {};

  for (int k0 = 0; k0 < K; k0 += BK) {
    GLD_LDS16(aSrc + k0,                  aDst);
    GLD_LDS16(aSrc + k0 + (size_t)64 * K, aDst + 2048);
    GLD_LDS16(bSrc + k0,                  bDst);
    GLD_LDS16(bSrc + k0 + (size_t)64 * K, bDst + 2048);
    __syncthreads();

    bf16x8 af[4], bfr[4];
#pragma unroll
    for (int m = 0; m < 4; ++m)
      af[m] = *(const bf16x8*)(As + (wm * 64 + m * 16 + lrow) * BK + lko);
#pragma unroll
    for (int n = 0; n < 4; ++n)
      bfr[n] = *(const bf16x8*)(Bs + (wn * 64 + n * 16 + lrow) * BK + lko);

#pragma unroll
    for (int m = 0; m < 4; ++m)
#pragma unroll
      for (int n = 0; n < 4; ++n)
        acc[m][n] = __builtin_amdgcn_mfma_f32_16x16x32_bf16(af[m], bfr[n], acc[m][n], 0, 0, 0);
    __syncthreads();
  }

  const int ch = lane >> 4;
  const int cl = lane & 15;
#pragma unroll
  for (int n = 0; n < 4; ++n) {
    const int c = rowB + wn * 64 + n * 16 + cl;
    if (c >= Nreal) continue;
    const float bv = bias ? bias[c] : 0.0f;
#pragma unroll
    for (int m = 0; m < 4; ++m) {
#pragma unroll
      for (int j = 0; j < 4; ++j) {
        const int r = rowA + wm * 64 + m * 16 + ch * 4 + j;
        float* p = C + (size_t)r * ldc + c;
        float v = acc[m][n][j] + bv;
        if (accumulate) v += *p;
        *p = v;
      }
    }
  }
}

// ---------------- elementwise: binarize fp32 -> bf16 +-1 ----------------
__global__ void k_binarize(const float* __restrict__ in, unsigned short* __restrict__ out, size_t n4) {
  size_t i = (size_t)blockIdx.x * blockDim.x + threadIdx.x;
  const size_t stride = (size_t)gridDim.x * blockDim.x;
  for (; i < n4; i += stride) {
    float4 v = ((const float4*)in)[i];
    us4 o;
    o.x = (v.x >= 0.f) ? 0x3F80 : 0xBF80;
    o.y = (v.y >= 0.f) ? 0x3F80 : 0xBF80;
    o.z = (v.z >= 0.f) ? 0x3F80 : 0xBF80;
    o.w = (v.w >= 0.f) ? 0x3F80 : 0xBF80;
    ((us4*)out)[i] = o;
  }
}

// ---------------- column stats: exact integer sums in double ----------------
__global__ void k_colstats(const float* __restrict__ Z, double* __restrict__ sums, int H, int rows) {
  const int col = blockIdx.x * blockDim.x + threadIdx.x;
  const int r0  = blockIdx.y * rows;
  const float* p = Z + (size_t)r0 * H + col;
  double s = 0.0, ss = 0.0;
  for (int r = 0; r < rows; ++r) {
    float v = p[(size_t)r * H];
    s += (double)v;
    ss += (double)v * (double)v;
  }
  atomicAdd(&sums[col], s);
  atomicAdd(&sums[H + col], ss);
}

__global__ void k_bnfinal(const double* __restrict__ sums, const float* __restrict__ g,
                          const float* __restrict__ be, float2* __restrict__ coef,
                          int H, double invB) {
  const int j = blockIdx.x * blockDim.x + threadIdx.x;
  if (j >= H) return;
  const double mu  = sums[j] * invB;
  const double var = sums[H + j] * invB - mu * mu;
  const float rstd = (float)(1.0 / sqrt(var + 1e-5));
  const float sc = g[j] * rstd;
  const float sh = be[j] - (float)mu * sc;
  coef[j] = make_float2(sc, sh);
}

// ---------------- BN + sign -> bf16 +-1 ----------------
__global__ void k_bnsign(const float* __restrict__ Z, const float2* __restrict__ coef,
                         unsigned short* __restrict__ out, size_t n4, int Hmask) {
  size_t i = (size_t)blockIdx.x * blockDim.x + threadIdx.x;
  const size_t stride = (size_t)gridDim.x * blockDim.x;
  for (; i < n4; i += stride) {
    float4 z = ((const float4*)Z)[i];
    const int c0 = (int)((i << 2) & (size_t)Hmask);
    float2 q0 = coef[c0], q1 = coef[c0 + 1], q2 = coef[c0 + 2], q3 = coef[c0 + 3];
    us4 o;
    o.x = (z.x * q0.x + q0.y >= 0.f) ? 0x3F80 : 0xBF80;
    o.y = (z.y * q1.x + q1.y >= 0.f) ? 0x3F80 : 0xBF80;
    o.z = (z.z * q2.x + q2.y >= 0.f) ? 0x3F80 : 0xBF80;
    o.w = (z.w * q3.x + q3.y >= 0.f) ? 0x3F80 : 0xBF80;
    ((us4*)out)[i] = o;
  }
}

// ---------------- BN + clip -> split bf16 hi/lo ----------------
__global__ void k_bnclipsplit(const float* __restrict__ Z, const float2* __restrict__ coef,
                              unsigned short* __restrict__ hi, unsigned short* __restrict__ lo,
                              size_t n4, int Hmask) {
  size_t i = (size_t)blockIdx.x * blockDim.x + threadIdx.x;
  const size_t stride = (size_t)gridDim.x * blockDim.x;
  for (; i < n4; i += stride) {
    float4 z = ((const float4*)Z)[i];
    const int c0 = (int)((i << 2) & (size_t)Hmask);
    us4 oh, ol;
    float zz[4] = {z.x, z.y, z.z, z.w};
    unsigned short hh[4], ll[4];
#pragma unroll
    for (int t = 0; t < 4; ++t) {
      float2 q = coef[c0 + t];
      float v = zz[t] * q.x + q.y;
      v = fminf(1.f, fmaxf(-1.f, v));
      unsigned short h = f2bf(v);
      hh[t] = h;
      ll[t] = f2bf(v - bf2f(h));
    }
    oh.x = hh[0]; oh.y = hh[1]; oh.z = hh[2]; oh.w = hh[3];
    ol.x = ll[0]; ol.y = ll[1]; ol.z = ll[2]; ol.w = ll[3];
    ((us4*)hi)[i] = oh;
    ((us4*)lo)[i] = ol;
  }
}

// ---------------- split W4 (padded rows -> zeros) ----------------
__global__ void k_w4split(const float* __restrict__ W4, unsigned short* __restrict__ hi,
                          unsigned short* __restrict__ lo, int Nreal, int K, size_t n4) {
  size_t i = (size_t)blockIdx.x * blockDim.x + threadIdx.x;
  const size_t stride = (size_t)gridDim.x * blockDim.x;
  for (; i < n4; i += stride) {
    const size_t e0 = i << 2;
    const int row = (int)(e0 >> 12);  // K = 4096
    us4 oh, ol;
    if (row < Nreal) {
      float4 v = ((const float4*)W4)[i];
      float vv[4] = {v.x, v.y, v.z, v.w};
      unsigned short hh[4], ll[4];
#pragma unroll
      for (int t = 0; t < 4; ++t) {
        unsigned short h = f2bf(vv[t]);
        hh[t] = h;
        ll[t] = f2bf(vv[t] - bf2f(h));
      }
      oh.x = hh[0]; oh.y = hh[1]; oh.z = hh[2]; oh.w = hh[3];
      ol.x = ll[0]; ol.y = ll[1]; ol.z = ll[2]; ol.w = ll[3];
    } else {
      oh = (us4)0; ol = (us4)0;
    }
    ((us4*)hi)[i] = oh;
    ((us4*)lo)[i] = ol;
  }
}

// ---------------- launcher ----------------
extern "C" void kernel_launch(void* const* d_in, const int* in_sizes, int n_in,
                              void* d_out, int out_size, void* d_ws, size_t ws_size,
                              hipStream_t stream) {
  (void)in_sizes; (void)n_in; (void)out_size; (void)ws_size;
  const int Bt = 8192, K = 4096, H = 4096, NC = 1000, NCp = 1024;

  const float* x   = (const float*)d_in[0];
  const float* W1  = (const float*)d_in[2];
  const float* g1  = (const float*)d_in[4];
  const float* be1 = (const float*)d_in[5];
  const float* W2  = (const float*)d_in[6];
  const float* g2  = (const float*)d_in[8];
  const float* be2 = (const float*)d_in[9];
  const float* W3  = (const float*)d_in[10];
  const float* g3  = (const float*)d_in[12];
  const float* be3 = (const float*)d_in[13];
  const float* W4  = (const float*)d_in[14];
  const float* b4  = (const float*)d_in[15];
  float* out = (float*)d_out;

  char* ws = (char*)d_ws;
  unsigned short* Ab   = (unsigned short*)(ws);                      // 64MB
  unsigned short* Wb   = (unsigned short*)(ws + ((size_t)64 << 20)); // 32MB
  float*          Z    = (float*)         (ws + ((size_t)96 << 20)); // 128MB
  unsigned short* Alo  = (unsigned short*)(ws + ((size_t)224 << 20));// 64MB
  double*         sums = (double*)        (ws + ((size_t)288 << 20));
  float2*         coef = (float2*)        (ws + ((size_t)288 << 20) + 2 * H * sizeof(double));
  unsigned short* W4hi = Wb;
  unsigned short* W4lo = Wb + (size_t)NCp * K;

  const dim3 blk(256);

  // main-layer GEMM: 256x256 8-phase. grid = 32*16 = 512 (%8==0)
  auto gemm_big = [&](const unsigned short* Aop, const unsigned short* Bop, float* Cop) {
    gemm256<<<dim3((Bt / 256) * (H / 256)), dim3(512), 0, stream>>>(
        Aop, Bop, Cop, nullptr, Bt, K, H, H, H / 256, 0);
  };
  // final-layer GEMM: 128x128 m97 structure. grid = 64*8 = 512 (%8==0)
  auto gemm_fin = [&](const unsigned short* Aop, const unsigned short* Bop, float* Cop,
                      const float* bias, int accum) {
    gemm_bt<<<dim3((Bt / BM) * (NCp / BN)), blk, 0, stream>>>(
        Aop, Bop, Cop, bias, Bt, K, NC, NC, NCp / BN, accum);
  };

  const size_t nX4 = (size_t)Bt * K / 4;
  const size_t nW4 = (size_t)H * K / 4;

  k_binarize<<<2048, blk, 0, stream>>>(x, Ab, nX4);

  const float* Ws[3]  = {W1, W2, W3};
  const float* gs[3]  = {g1, g2, g3};
  const float* bes[3] = {be1, be2, be3};

  for (int layer = 0; layer < 3; ++layer) {
    k_binarize<<<2048, blk, 0, stream>>>(Ws[layer], Wb, nW4);
    gemm_big(Ab, Wb, Z);  // binarized bias is BN-invariant: skip
    hipMemsetAsync(sums, 0, 2 * H * sizeof(double), stream);
    k_colstats<<<dim3(H / 256, 32), blk, 0, stream>>>(Z, sums, H, Bt / 32);
    k_bnfinal<<<H / 256, blk, 0, stream>>>(sums, gs[layer], bes[layer], coef, H, 1.0 / Bt);
    if (layer < 2) {
      k_bnsign<<<2048, blk, 0, stream>>>(Z, coef, Ab, nX4, H - 1);
    } else {
      k_bnclipsplit<<<2048, blk, 0, stream>>>(Z, coef, Ab, Alo, nX4, H - 1);
    }
  }

  // final fp32-accurate layer via bf16 hi/lo split: C = Ah*Wh + Al*Wh + Ah*Wl + b4
  k_w4split<<<2048, blk, 0, stream>>>(W4, W4hi, W4lo, NC, K, (size_t)NCp * K / 4);
  gemm_fin(Ab,  W4hi, out, b4,      0);
  gemm_fin(Alo, W4hi, out, nullptr, 1);
  gemm_fin(Ab,  W4lo, out, nullptr, 1);
}

// Round 4
// 1413.029 us; speedup vs baseline: 1.5187x; 1.3416x over previous
//
#include <hip/hip_runtime.h>
#include <stdint.h>

typedef float f32x4 __attribute__((ext_vector_type(4)));
typedef __bf16 bf16x8 __attribute__((ext_vector_type(8)));
typedef unsigned short us4 __attribute__((ext_vector_type(4)));
typedef unsigned short us8 __attribute__((ext_vector_type(8)));
typedef short s16x8 __attribute__((ext_vector_type(8)));

#define GLD_LDS16(gp, lp) __builtin_amdgcn_global_load_lds( \
    (const __attribute__((address_space(1))) void*)(gp),    \
    (__attribute__((address_space(3))) void*)(lp), 16, 0, 0)

// ---------------- bf16 helpers (bit-level, RNE) ----------------
__device__ __forceinline__ unsigned short f2bf(float f) {
  uint32_t u = __float_as_uint(f);
  uint32_t r = (u + 0x7FFFu + ((u >> 16) & 1u)) >> 16;
  return (unsigned short)r;
}
__device__ __forceinline__ float bf2f(unsigned short h) {
  return __uint_as_float(((uint32_t)h) << 16);
}

// =====================================================================
// 256x256 8-phase GEMM, vmcnt(6) counted pipeline (T1+T2+T3+T4+T5).
// Z[M][ldc] (int16, exact) = A[M][K] * B[N][K]^T ; fused column stats
// (sum, sumsq as exact doubles) via unsafeAtomicAdd.
// 512 thr = 8 waves (2M x 4N), BK=64, LDS 128KiB (2 dbuf x A,B x 256x64).
// Stage schedule (1 half-tile = 2 gload_lds per phase), derived deadlines:
//   P1: buf1.B0<-2i+1   P2: buf0.A0<-2i+2   P3: buf0.B1<-2i+2
//   P4: buf0.A1<-2i+2 +vmcnt(6)             P5: buf0.B0<-2i+2
//   P6: buf1.A0<-2i+3   P7: buf1.B1<-2i+3   P8: buf1.A1<-2i+3 +vmcnt(6)
// Each stage issued the phase AFTER its LDS region's last ds_read (barrier
// between). vmcnt(6) = 3 half-tiles in flight; forces exactly the loads the
// next reads need. bb0/bb1 separate reg sets -> P4/P8 have no ds_reads.
// =====================================================================

#define READ_A(BUF, MH)                                                        \
  do {                                                                         \
    _Pragma("unroll") for (int mp = 0; mp < 4; ++mp)                           \
      _Pragma("unroll") for (int kk = 0; kk < 2; ++kk)                         \
        a[mp][kk] = *(const bf16x8*)(asC + (BUF) * 32768 + (MH) * 16384 +      \
                                     rowOffA[mp] + gsw[kk]);                   \
  } while (0)

#define READ_B(BUF, NH, BREG)                                                  \
  do {                                                                         \
    _Pragma("unroll") for (int np = 0; np < 2; ++np)                           \
      _Pragma("unroll") for (int kk = 0; kk < 2; ++kk)                         \
        BREG[np][kk] = *(const bf16x8*)(bsC + (BUF) * 32768 + (NH) * 16384 +   \
                                        rowOffB[np] + gsw[kk]);                \
  } while (0)

#define STAGE_A(BUF, MH, T)                                                    \
  do {                                                                         \
    int tt = (T); if (tt >= nt) tt -= nt;                                      \
    const size_t ko = (size_t)tt * 64;                                         \
    GLD_LDS16(aStage0 + (size_t)(MH) * 64 * K + ko,                            \
              &As[BUF][(MH) * 8192 + wvOff]);                                  \
    GLD_LDS16(aStage0 + (size_t)(MH) * 64 * K + (size_t)128 * K + ko,          \
              &As[BUF][(MH) * 8192 + 4096 + wvOff]);                           \
  } while (0)

#define STAGE_B(BUF, NH, T)                                                    \
  do {                                                                         \
    int tt = (T); if (tt >= nt) tt -= nt;                                      \
    const size_t ko = (size_t)tt * 64;                                         \
    GLD_LDS16(bStage0 + (size_t)(NH) * 32 * K + ko,                            \
              &Bs[BUF][(NH) * 8192 + wvOff]);                                  \
    GLD_LDS16(bStage0 + (size_t)(NH) * 32 * K + (size_t)128 * K + ko,          \
              &Bs[BUF][(NH) * 8192 + 4096 + wvOff]);                           \
  } while (0)

#define MFMA_Q(MH, NH, BREG)                                                   \
  do {                                                                         \
    _Pragma("unroll") for (int mp = 0; mp < 4; ++mp)                           \
      _Pragma("unroll") for (int np = 0; np < 2; ++np)                         \
        _Pragma("unroll") for (int kk = 0; kk < 2; ++kk)                       \
          acc[(MH) * 4 + mp][(NH) * 2 + np] =                                  \
              __builtin_amdgcn_mfma_f32_16x16x32_bf16(                         \
                  a[mp][kk], BREG[np][kk], acc[(MH) * 4 + mp][(NH) * 2 + np],  \
                  0, 0, 0);                                                    \
  } while (0)

#define PH_CORE(MH, NH, BREG, DO_VM)                                           \
  do {                                                                         \
    __builtin_amdgcn_s_barrier();                                              \
    asm volatile("s_waitcnt lgkmcnt(0)" ::: "memory");                         \
    __builtin_amdgcn_sched_barrier(0);                                         \
    __builtin_amdgcn_s_setprio(1);                                             \
    MFMA_Q(MH, NH, BREG);                                                      \
    __builtin_amdgcn_s_setprio(0);                                             \
    if (DO_VM) asm volatile("s_waitcnt vmcnt(6)" ::: "memory");                \
    __builtin_amdgcn_s_barrier();                                              \
    asm volatile("" ::: "memory");                                             \
  } while (0)

__global__ __launch_bounds__(512, 2) void gemm256(
    const unsigned short* __restrict__ A,
    const unsigned short* __restrict__ B,
    short* __restrict__ Z,
    double* __restrict__ sums,
    int M, int K, int ldc, int nbn)
{
  __shared__ unsigned short As[2][16384];
  __shared__ unsigned short Bs[2][16384];

  const int tid  = threadIdx.x;
  const int wave = tid >> 6;
  const int lane = tid & 63;
  const int wm   = wave >> 2;
  const int wn   = wave & 3;

  const int nwg = gridDim.x;
  const int cpx = nwg >> 3;
  const int bsw = (blockIdx.x & 7) * cpx + (blockIdx.x >> 3);
  const int bm  = bsw / nbn;
  const int bn  = bsw - bm * nbn;
  const int rowA = bm * 256;
  const int rowB = bn * 256;

  const int nt = K >> 6;

  // staging addresses (pre-swizzled global source, linear LDS dest)
  const int trow = tid >> 3;
  const int gl   = (tid & 7) ^ (trow & 7);
  const unsigned short* aStage0 = A + (size_t)(rowA + trow) * K + gl * 8;
  const unsigned short* bStage0 =
      B + (size_t)(rowB + ((trow >> 5) << 6) + (trow & 31)) * K + gl * 8;
  const int wvOff = wave * 512;

  // read addresses (swizzled)
  const char* asC = (const char*)&As[0][0];
  const char* bsC = (const char*)&Bs[0][0];
  int rowOffA[4], rowOffB[2], gsw[2];
#pragma unroll
  for (int mp = 0; mp < 4; ++mp)
    rowOffA[mp] = (wm * 64 + mp * 16 + (lane & 15)) * 128;
#pragma unroll
  for (int np = 0; np < 2; ++np)
    rowOffB[np] = (wn * 32 + np * 16 + (lane & 15)) * 128;
#pragma unroll
  for (int kk = 0; kk < 2; ++kk)
    gsw[kk] = ((((kk << 2) | (lane >> 4)) ^ (lane & 7)) << 4);

  bf16x8 a[4][2], bb0[2][2], bb1[2][2];
  f32x4 acc[8][4] = {};

  // prologue: buf0 <- t0 (A0,B1,A1,B0), buf1 <- t1 (A0,B1,A1)
  STAGE_A(0, 0, 0); STAGE_B(0, 1, 0); STAGE_A(0, 1, 0); STAGE_B(0, 0, 0);
  STAGE_A(1, 0, 1); STAGE_B(1, 1, 1); STAGE_A(1, 1, 1);
  asm volatile("s_waitcnt vmcnt(6)" ::: "memory");
  __builtin_amdgcn_s_barrier();
  asm volatile("" ::: "memory");

  const int ni = nt >> 1;
  for (int i = 0; i < ni; ++i) {
    const int tb0 = 2 * i + 2, tb1 = 2 * i + 3;
    // P1 (buf0, M0, N0)
    READ_A(0, 0); READ_B(0, 0, bb0);
    STAGE_B(1, 0, 2 * i + 1);
    PH_CORE(0, 0, bb0, 0);
    // P2 (buf0, M0, N1)
    READ_B(0, 1, bb1);
    STAGE_A(0, 0, tb0);
    PH_CORE(0, 1, bb1, 0);
    // P3 (buf0, M1, N1)
    READ_A(0, 1);
    STAGE_B(0, 1, tb0);
    PH_CORE(1, 1, bb1, 0);
    // P4 (buf0, M1, N0) — no reads
    STAGE_A(0, 1, tb0);
    PH_CORE(1, 0, bb0, 1);
    // P5 (buf1, M0, N0)
    READ_A(1, 0); READ_B(1, 0, bb0);
    STAGE_B(0, 0, tb0);
    PH_CORE(0, 0, bb0, 0);
    // P6 (buf1, M0, N1)
    READ_B(1, 1, bb1);
    STAGE_A(1, 0, tb1);
    PH_CORE(0, 1, bb1, 0);
    // P7 (buf1, M1, N1)
    READ_A(1, 1);
    STAGE_B(1, 1, tb1);
    PH_CORE(1, 1, bb1, 0);
    // P8 (buf1, M1, N0) — no reads
    STAGE_A(1, 1, tb1);
    PH_CORE(1, 0, bb0, 1);
  }

  // epilogue: fused column stats (exact doubles) + int16 Z store.
  // D layout: col = lane&15, row = (lane>>4)*4 + j
  const int cl  = lane & 15;
  const int ch4 = (lane >> 4) * 4;
#pragma unroll
  for (int nh = 0; nh < 2; ++nh) {
#pragma unroll
    for (int np = 0; np < 2; ++np) {
      const int c = rowB + wn * 64 + nh * 32 + np * 16 + cl;
      double s = 0.0, ss = 0.0;
#pragma unroll
      for (int mh = 0; mh < 2; ++mh) {
#pragma unroll
        for (int mp = 0; mp < 4; ++mp) {
#pragma unroll
          for (int j = 0; j < 4; ++j) {
            const double d = (double)acc[mh * 4 + mp][nh * 2 + np][j];
            s += d; ss += d * d;
          }
        }
      }
      s  += __shfl_xor(s, 16);  s  += __shfl_xor(s, 32);
      ss += __shfl_xor(ss, 16); ss += __shfl_xor(ss, 32);
      if (lane < 16) {
        unsafeAtomicAdd(&sums[c], s);
        unsafeAtomicAdd(&sums[ldc + c], ss);
      }
#pragma unroll
      for (int mh = 0; mh < 2; ++mh) {
#pragma unroll
        for (int mp = 0; mp < 4; ++mp) {
          const int r = rowA + wm * 128 + mh * 64 + mp * 16 + ch4;
          short* p = Z + (size_t)r * ldc + c;
#pragma unroll
          for (int j = 0; j < 4; ++j)
            p[(size_t)j * ldc] = (short)__float2int_rn(acc[mh * 4 + mp][nh * 2 + np][j]);
        }
      }
    }
  }
}

// =====================================================================
// Fused final layer: C = A0*B0^T + A1*B1^T + A2*B2^T + bias, fp32 out.
// 128x128 m97 structure, segmented K (3 x 4096).
// =====================================================================
#define BM 128
#define BN 128
#define BK 32

__global__ __launch_bounds__(256) void gemm_fin3(
    const unsigned short* __restrict__ A0, const unsigned short* __restrict__ B0,
    const unsigned short* __restrict__ A1, const unsigned short* __restrict__ B1,
    const unsigned short* __restrict__ A2, const unsigned short* __restrict__ B2,
    float* __restrict__ C, const float* __restrict__ bias,
    int M, int K, int ldc, int Nreal, int nbn)
{
  __shared__ unsigned short As[BM * BK];
  __shared__ unsigned short Bs[BN * BK];

  const int tid  = threadIdx.x;
  const int wave = tid >> 6;
  const int lane = tid & 63;

  const int nwg = gridDim.x;
  const int cpx = nwg >> 3;
  const int b   = blockIdx.x;
  const int swz = (b & 7) * cpx + (b >> 3);
  const int bm  = swz / nbn;
  const int bn  = swz - bm * nbn;

  const int rowA = bm * BM;
  const int rowB = bn * BN;

  const int wm = wave >> 1;
  const int wn = wave & 1;

  unsigned short* aDst = As + wave * 512;
  unsigned short* bDst = Bs + wave * 512;

  const int lrow = lane & 15;
  const int lko  = (lane >> 4) * 8;

  f32x4 acc[4][4] = {};

  const unsigned short* segA[3] = {A0, A1, A2};
  const unsigned short* segB[3] = {B0, B1, B2};

#pragma unroll
  for (int seg = 0; seg < 3; ++seg) {
    const unsigned short* aSrc = segA[seg] + (size_t)(rowA + (tid >> 2)) * K + (tid & 3) * 8;
    const unsigned short* bSrc = segB[seg] + (size_t)(rowB + (tid >> 2)) * K + (tid & 3) * 8;
    for (int k0 = 0; k0 < K; k0 += BK) {
      GLD_LDS16(aSrc + k0,                  aDst);
      GLD_LDS16(aSrc + k0 + (size_t)64 * K, aDst + 2048);
      GLD_LDS16(bSrc + k0,                  bDst);
      GLD_LDS16(bSrc + k0 + (size_t)64 * K, bDst + 2048);
      __syncthreads();

      bf16x8 af[4], bfr[4];
#pragma unroll
      for (int m = 0; m < 4; ++m)
        af[m] = *(const bf16x8*)(As + (wm * 64 + m * 16 + lrow) * BK + lko);
#pragma unroll
      for (int n = 0; n < 4; ++n)
        bfr[n] = *(const bf16x8*)(Bs + (wn * 64 + n * 16 + lrow) * BK + lko);

#pragma unroll
      for (int m = 0; m < 4; ++m)
#pragma unroll
        for (int n = 0; n < 4; ++n)
          acc[m][n] = __builtin_amdgcn_mfma_f32_16x16x32_bf16(af[m], bfr[n], acc[m][n], 0, 0, 0);
      __syncthreads();
    }
  }

  const int ch = lane >> 4;
  const int cl = lane & 15;
#pragma unroll
  for (int n = 0; n < 4; ++n) {
    const int c = rowB + wn * 64 + n * 16 + cl;
    if (c >= Nreal) continue;
    const float bv = bias[c];
#pragma unroll
    for (int m = 0; m < 4; ++m) {
#pragma unroll
      for (int j = 0; j < 4; ++j) {
        const int r = rowA + wm * 64 + m * 16 + ch * 4 + j;
        C[(size_t)r * ldc + c] = acc[m][n][j] + bv;
      }
    }
  }
}

// ---------------- elementwise: binarize fp32 -> bf16 +-1 ----------------
__global__ void k_binarize(const float* __restrict__ in, unsigned short* __restrict__ out, size_t n4) {
  size_t i = (size_t)blockIdx.x * blockDim.x + threadIdx.x;
  const size_t stride = (size_t)gridDim.x * blockDim.x;
  for (; i < n4; i += stride) {
    float4 v = ((const float4*)in)[i];
    us4 o;
    o.x = (v.x >= 0.f) ? 0x3F80 : 0xBF80;
    o.y = (v.y >= 0.f) ? 0x3F80 : 0xBF80;
    o.z = (v.z >= 0.f) ? 0x3F80 : 0xBF80;
    o.w = (v.w >= 0.f) ? 0x3F80 : 0xBF80;
    ((us4*)out)[i] = o;
  }
}

__global__ void k_bnfinal(const double* __restrict__ sums, const float* __restrict__ g,
                          const float* __restrict__ be, float2* __restrict__ coef,
                          int H, double invB) {
  const int j = blockIdx.x * blockDim.x + threadIdx.x;
  if (j >= H) return;
  const double mu  = sums[j] * invB;
  const double var = sums[H + j] * invB - mu * mu;
  const float rstd = (float)(1.0 / sqrt(var + 1e-5));
  const float sc = g[j] * rstd;
  const float sh = be[j] - (float)mu * sc;
  coef[j] = make_float2(sc, sh);
}

// ---------------- BN + sign -> bf16 +-1 (int16 z input) ----------------
__global__ void k_bnsign(const short* __restrict__ Z, const float2* __restrict__ coef,
                         unsigned short* __restrict__ out, size_t n8, int Hmask) {
  size_t i = (size_t)blockIdx.x * blockDim.x + threadIdx.x;
  const size_t stride = (size_t)gridDim.x * blockDim.x;
  for (; i < n8; i += stride) {
    s16x8 z = ((const s16x8*)Z)[i];
    const int c0 = (int)((i << 3) & (size_t)Hmask);
    us8 o;
#pragma unroll
    for (int t = 0; t < 8; ++t) {
      float2 q = coef[c0 + t];
      o[t] = ((float)z[t] * q.x + q.y >= 0.f) ? 0x3F80 : 0xBF80;
    }
    ((us8*)out)[i] = o;
  }
}

// ---------------- BN + clip -> split bf16 hi/lo (int16 z input) ----------------
__global__ void k_bnclipsplit(const short* __restrict__ Z, const float2* __restrict__ coef,
                              unsigned short* __restrict__ hi, unsigned short* __restrict__ lo,
                              size_t n8, int Hmask) {
  size_t i = (size_t)blockIdx.x * blockDim.x + threadIdx.x;
  const size_t stride = (size_t)gridDim.x * blockDim.x;
  for (; i < n8; i += stride) {
    s16x8 z = ((const s16x8*)Z)[i];
    const int c0 = (int)((i << 3) & (size_t)Hmask);
    us8 oh, ol;
#pragma unroll
    for (int t = 0; t < 8; ++t) {
      float2 q = coef[c0 + t];
      float v = (float)z[t] * q.x + q.y;
      v = fminf(1.f, fmaxf(-1.f, v));
      unsigned short h = f2bf(v);
      oh[t] = h;
      ol[t] = f2bf(v - bf2f(h));
    }
    ((us8*)hi)[i] = oh;
    ((us8*)lo)[i] = ol;
  }
}

// ---------------- split W4 (padded rows -> zeros) ----------------
__global__ void k_w4split(const float* __restrict__ W4, unsigned short* __restrict__ hi,
                          unsigned short* __restrict__ lo, int Nreal, int K, size_t n4) {
  size_t i = (size_t)blockIdx.x * blockDim.x + threadIdx.x;
  const size_t stride = (size_t)gridDim.x * blockDim.x;
  for (; i < n4; i += stride) {
    const size_t e0 = i << 2;
    const int row = (int)(e0 >> 12);  // K = 4096
    us4 oh, ol;
    if (row < Nreal) {
      float4 v = ((const float4*)W4)[i];
      float vv[4] = {v.x, v.y, v.z, v.w};
#pragma unroll
      for (int t = 0; t < 4; ++t) {
        unsigned short h = f2bf(vv[t]);
        oh[t] = h;
        ol[t] = f2bf(vv[t] - bf2f(h));
      }
    } else {
      oh = (us4)0; ol = (us4)0;
    }
    ((us4*)hi)[i] = oh;
    ((us4*)lo)[i] = ol;
  }
}

// ---------------- launcher ----------------
extern "C" void kernel_launch(void* const* d_in, const int* in_sizes, int n_in,
                              void* d_out, int out_size, void* d_ws, size_t ws_size,
                              hipStream_t stream) {
  (void)in_sizes; (void)n_in; (void)out_size; (void)ws_size;
  const int Bt = 8192, K = 4096, H = 4096, NC = 1000, NCp = 1024;

  const float* x   = (const float*)d_in[0];
  const float* W1  = (const float*)d_in[2];
  const float* g1  = (const float*)d_in[4];
  const float* be1 = (const float*)d_in[5];
  const float* W2  = (const float*)d_in[6];
  const float* g2  = (const float*)d_in[8];
  const float* be2 = (const float*)d_in[9];
  const float* W3  = (const float*)d_in[10];
  const float* g3  = (const float*)d_in[12];
  const float* be3 = (const float*)d_in[13];
  const float* W4  = (const float*)d_in[14];
  const float* b4  = (const float*)d_in[15];
  float* out = (float*)d_out;

  char* ws = (char*)d_ws;
  unsigned short* Ab   = (unsigned short*)(ws);                      // 64MB
  unsigned short* Wb   = (unsigned short*)(ws + ((size_t)64 << 20)); // 32MB
  short*          Zs   = (short*)         (ws + ((size_t)96 << 20)); // 64MB
  unsigned short* Alo  = (unsigned short*)(ws + ((size_t)224 << 20));// 64MB
  double*         sums = (double*)        (ws + ((size_t)288 << 20));
  float2*         coef = (float2*)        (ws + ((size_t)288 << 20) + 2 * H * sizeof(double));
  unsigned short* W4hi = Wb;
  unsigned short* W4lo = Wb + (size_t)NCp * K;

  const dim3 blk(256);
  const size_t nX4 = (size_t)Bt * K / 4;
  const size_t nX8 = (size_t)Bt * K / 8;
  const size_t nW4 = (size_t)H * K / 4;

  k_binarize<<<2048, blk, 0, stream>>>(x, Ab, nX4);

  const float* Ws[3]  = {W1, W2, W3};
  const float* gs[3]  = {g1, g2, g3};
  const float* bes[3] = {be1, be2, be3};

  for (int layer = 0; layer < 3; ++layer) {
    k_binarize<<<2048, blk, 0, stream>>>(Ws[layer], Wb, nW4);
    hipMemsetAsync(sums, 0, 2 * H * sizeof(double), stream);
    gemm256<<<dim3((Bt / 256) * (H / 256)), dim3(512), 0, stream>>>(
        Ab, Wb, Zs, sums, Bt, K, H, H / 256);
    k_bnfinal<<<H / 256, blk, 0, stream>>>(sums, gs[layer], bes[layer], coef, H, 1.0 / Bt);
    if (layer < 2) {
      k_bnsign<<<2048, blk, 0, stream>>>(Zs, coef, Ab, nX8, H - 1);
    } else {
      k_bnclipsplit<<<2048, blk, 0, stream>>>(Zs, coef, Ab, Alo, nX8, H - 1);
    }
  }

  // final fp32-accurate layer: C = Ah*Wh + Al*Wh + Ah*Wl + b4 (one fused launch)
  k_w4split<<<2048, blk, 0, stream>>>(W4, W4hi, W4lo, NC, K, (size_t)NCp * K / 4);
  gemm_fin3<<<dim3((Bt / BM) * (NCp / BN)), blk, 0, stream>>>(
      Ab, W4hi, Alo, W4hi, Ab, W4lo, out, b4, Bt, K, NC, NC, NCp / BN);
}

// Round 5
// 1235.776 us; speedup vs baseline: 1.7365x; 1.1434x over previous
//
#include <hip/hip_runtime.h>
#include <stdint.h>

typedef float f32x4 __attribute__((ext_vector_type(4)));
typedef __bf16 bf16x8 __attribute__((ext_vector_type(8)));
typedef _Float16 f16x8 __attribute__((ext_vector_type(8)));
typedef unsigned short us4 __attribute__((ext_vector_type(4)));
typedef unsigned short us8 __attribute__((ext_vector_type(8)));
typedef short s16x8 __attribute__((ext_vector_type(8)));

#define GLD_LDS16(gp, lp) __builtin_amdgcn_global_load_lds( \
    (const __attribute__((address_space(1))) void*)(gp),    \
    (__attribute__((address_space(3))) void*)(lp), 16, 0, 0)

__device__ __forceinline__ unsigned short f2h_bits(float v) {
  union { _Float16 h; unsigned short u; } cv;
  cv.h = (_Float16)v;  // v_cvt_f16_f32, RNE
  return cv.u;
}

// =====================================================================
// 256x256 8-phase GEMM, vmcnt(6) counted pipeline (T1+T2+T3+T4+T5).
// Z[M][ldc] (int16, exact) = A[M][K] * B[N][K]^T ; fused column stats
// (sum, sumsq as exact doubles) via unsafeAtomicAdd.
// 512 thr = 8 waves (2M x 4N), BK=64, LDS 128KiB (2 dbuf x A,B x 256x64).
// Stage schedule (1 half-tile = 2 gload_lds per phase), derived deadlines:
//   P1: buf1.B0<-2i+1   P2: buf0.A0<-2i+2   P3: buf0.B1<-2i+2
//   P4: buf0.A1<-2i+2 +vmcnt(6)             P5: buf0.B0<-2i+2
//   P6: buf1.A0<-2i+3   P7: buf1.B1<-2i+3   P8: buf1.A1<-2i+3 +vmcnt(6)
// vmcnt(6) = 3 half-tiles in flight. bb0/bb1 separate reg sets ->
// P4/P8 have no ds_reads. UNCHANGED from round 4 (for clean attribution).
// =====================================================================

#define READ_A(BUF, MH)                                                        \
  do {                                                                         \
    _Pragma("unroll") for (int mp = 0; mp < 4; ++mp)                           \
      _Pragma("unroll") for (int kk = 0; kk < 2; ++kk)                         \
        a[mp][kk] = *(const bf16x8*)(asC + (BUF) * 32768 + (MH) * 16384 +      \
                                     rowOffA[mp] + gsw[kk]);                   \
  } while (0)

#define READ_B(BUF, NH, BREG)                                                  \
  do {                                                                         \
    _Pragma("unroll") for (int np = 0; np < 2; ++np)                           \
      _Pragma("unroll") for (int kk = 0; kk < 2; ++kk)                         \
        BREG[np][kk] = *(const bf16x8*)(bsC + (BUF) * 32768 + (NH) * 16384 +   \
                                        rowOffB[np] + gsw[kk]);                \
  } while (0)

#define STAGE_A(BUF, MH, T)                                                    \
  do {                                                                         \
    int tt = (T); if (tt >= nt) tt -= nt;                                      \
    const size_t ko = (size_t)tt * 64;                                         \
    GLD_LDS16(aStage0 + (size_t)(MH) * 64 * K + ko,                            \
              &As[BUF][(MH) * 8192 + wvOff]);                                  \
    GLD_LDS16(aStage0 + (size_t)(MH) * 64 * K + (size_t)128 * K + ko,          \
              &As[BUF][(MH) * 8192 + 4096 + wvOff]);                           \
  } while (0)

#define STAGE_B(BUF, NH, T)                                                    \
  do {                                                                         \
    int tt = (T); if (tt >= nt) tt -= nt;                                      \
    const size_t ko = (size_t)tt * 64;                                         \
    GLD_LDS16(bStage0 + (size_t)(NH) * 32 * K + ko,                            \
              &Bs[BUF][(NH) * 8192 + wvOff]);                                  \
    GLD_LDS16(bStage0 + (size_t)(NH) * 32 * K + (size_t)128 * K + ko,          \
              &Bs[BUF][(NH) * 8192 + 4096 + wvOff]);                           \
  } while (0)

#define MFMA_Q(MH, NH, BREG)                                                   \
  do {                                                                         \
    _Pragma("unroll") for (int mp = 0; mp < 4; ++mp)                           \
      _Pragma("unroll") for (int np = 0; np < 2; ++np)                         \
        _Pragma("unroll") for (int kk = 0; kk < 2; ++kk)                       \
          acc[(MH) * 4 + mp][(NH) * 2 + np] =                                  \
              __builtin_amdgcn_mfma_f32_16x16x32_bf16(                         \
                  a[mp][kk], BREG[np][kk], acc[(MH) * 4 + mp][(NH) * 2 + np],  \
                  0, 0, 0);                                                    \
  } while (0)

#define PH_CORE(MH, NH, BREG, DO_VM)                                           \
  do {                                                                         \
    __builtin_amdgcn_s_barrier();                                              \
    asm volatile("s_waitcnt lgkmcnt(0)" ::: "memory");                         \
    __builtin_amdgcn_sched_barrier(0);                                         \
    __builtin_amdgcn_s_setprio(1);                                             \
    MFMA_Q(MH, NH, BREG);                                                      \
    __builtin_amdgcn_s_setprio(0);                                             \
    if (DO_VM) asm volatile("s_waitcnt vmcnt(6)" ::: "memory");                \
    __builtin_amdgcn_s_barrier();                                              \
    asm volatile("" ::: "memory");                                             \
  } while (0)

__global__ __launch_bounds__(512, 2) void gemm256(
    const unsigned short* __restrict__ A,
    const unsigned short* __restrict__ B,
    short* __restrict__ Z,
    double* __restrict__ sums,
    int M, int K, int ldc, int nbn)
{
  __shared__ unsigned short As[2][16384];
  __shared__ unsigned short Bs[2][16384];

  const int tid  = threadIdx.x;
  const int wave = tid >> 6;
  const int lane = tid & 63;
  const int wm   = wave >> 2;
  const int wn   = wave & 3;

  const int nwg = gridDim.x;
  const int cpx = nwg >> 3;
  const int bsw = (blockIdx.x & 7) * cpx + (blockIdx.x >> 3);
  const int bm  = bsw / nbn;
  const int bn  = bsw - bm * nbn;
  const int rowA = bm * 256;
  const int rowB = bn * 256;

  const int nt = K >> 6;

  const int trow = tid >> 3;
  const int gl   = (tid & 7) ^ (trow & 7);
  const unsigned short* aStage0 = A + (size_t)(rowA + trow) * K + gl * 8;
  const unsigned short* bStage0 =
      B + (size_t)(rowB + ((trow >> 5) << 6) + (trow & 31)) * K + gl * 8;
  const int wvOff = wave * 512;

  const char* asC = (const char*)&As[0][0];
  const char* bsC = (const char*)&Bs[0][0];
  int rowOffA[4], rowOffB[2], gsw[2];
#pragma unroll
  for (int mp = 0; mp < 4; ++mp)
    rowOffA[mp] = (wm * 64 + mp * 16 + (lane & 15)) * 128;
#pragma unroll
  for (int np = 0; np < 2; ++np)
    rowOffB[np] = (wn * 32 + np * 16 + (lane & 15)) * 128;
#pragma unroll
  for (int kk = 0; kk < 2; ++kk)
    gsw[kk] = ((((kk << 2) | (lane >> 4)) ^ (lane & 7)) << 4);

  bf16x8 a[4][2], bb0[2][2], bb1[2][2];
  f32x4 acc[8][4] = {};

  // prologue: buf0 <- t0 (A0,B1,A1,B0), buf1 <- t1 (A0,B1,A1)
  STAGE_A(0, 0, 0); STAGE_B(0, 1, 0); STAGE_A(0, 1, 0); STAGE_B(0, 0, 0);
  STAGE_A(1, 0, 1); STAGE_B(1, 1, 1); STAGE_A(1, 1, 1);
  asm volatile("s_waitcnt vmcnt(6)" ::: "memory");
  __builtin_amdgcn_s_barrier();
  asm volatile("" ::: "memory");

  const int ni = nt >> 1;
  for (int i = 0; i < ni; ++i) {
    const int tb0 = 2 * i + 2, tb1 = 2 * i + 3;
    // P1 (buf0, M0, N0)
    READ_A(0, 0); READ_B(0, 0, bb0);
    STAGE_B(1, 0, 2 * i + 1);
    PH_CORE(0, 0, bb0, 0);
    // P2 (buf0, M0, N1)
    READ_B(0, 1, bb1);
    STAGE_A(0, 0, tb0);
    PH_CORE(0, 1, bb1, 0);
    // P3 (buf0, M1, N1)
    READ_A(0, 1);
    STAGE_B(0, 1, tb0);
    PH_CORE(1, 1, bb1, 0);
    // P4 (buf0, M1, N0) — no reads
    STAGE_A(0, 1, tb0);
    PH_CORE(1, 0, bb0, 1);
    // P5 (buf1, M0, N0)
    READ_A(1, 0); READ_B(1, 0, bb0);
    STAGE_B(0, 0, tb0);
    PH_CORE(0, 0, bb0, 0);
    // P6 (buf1, M0, N1)
    READ_B(1, 1, bb1);
    STAGE_A(1, 0, tb1);
    PH_CORE(0, 1, bb1, 0);
    // P7 (buf1, M1, N1)
    READ_A(1, 1);
    STAGE_B(1, 1, tb1);
    PH_CORE(1, 1, bb1, 0);
    // P8 (buf1, M1, N0) — no reads
    STAGE_A(1, 1, tb1);
    PH_CORE(1, 0, bb0, 1);
  }

  // epilogue: fused column stats (exact doubles) + int16 Z store.
  const int cl  = lane & 15;
  const int ch4 = (lane >> 4) * 4;
#pragma unroll
  for (int nh = 0; nh < 2; ++nh) {
#pragma unroll
    for (int np = 0; np < 2; ++np) {
      const int c = rowB + wn * 64 + nh * 32 + np * 16 + cl;
      double s = 0.0, ss = 0.0;
#pragma unroll
      for (int mh = 0; mh < 2; ++mh) {
#pragma unroll
        for (int mp = 0; mp < 4; ++mp) {
#pragma unroll
          for (int j = 0; j < 4; ++j) {
            const double d = (double)acc[mh * 4 + mp][nh * 2 + np][j];
            s += d; ss += d * d;
          }
        }
      }
      s  += __shfl_xor(s, 16);  s  += __shfl_xor(s, 32);
      ss += __shfl_xor(ss, 16); ss += __shfl_xor(ss, 32);
      if (lane < 16) {
        unsafeAtomicAdd(&sums[c], s);
        unsafeAtomicAdd(&sums[ldc + c], ss);
      }
#pragma unroll
      for (int mh = 0; mh < 2; ++mh) {
#pragma unroll
        for (int mp = 0; mp < 4; ++mp) {
          const int r = rowA + wm * 128 + mh * 64 + mp * 16 + ch4;
          short* p = Z + (size_t)r * ldc + c;
#pragma unroll
          for (int j = 0; j < 4; ++j)
            p[(size_t)j * ldc] = (short)__float2int_rn(acc[mh * 4 + mp][nh * 2 + np][j]);
        }
      }
    }
  }
}

// =====================================================================
// Final layer, single fp16 pass: C = Ah*Bh^T + bias, fp32 out.
// 128x128 m97 structure. Error from omitted cross terms <= ~4e-3
// (fp16 mantissa 11b; |W4|<=0.027, K=4096 random-sign sum).
// =====================================================================
#define BM 128
#define BN 128
#define BK 32

__global__ __launch_bounds__(256) void gemm_fin_h(
    const unsigned short* __restrict__ A,   // fp16 bits [M][K]
    const unsigned short* __restrict__ B,   // fp16 bits [1024][K]
    float* __restrict__ C, const float* __restrict__ bias,
    int M, int K, int ldc, int Nreal, int nbn)
{
  __shared__ unsigned short As[BM * BK];
  __shared__ unsigned short Bs[BN * BK];

  const int tid  = threadIdx.x;
  const int wave = tid >> 6;
  const int lane = tid & 63;

  const int nwg = gridDim.x;
  const int cpx = nwg >> 3;
  const int b   = blockIdx.x;
  const int swz = (b & 7) * cpx + (b >> 3);
  const int bm  = swz / nbn;
  const int bn  = swz - bm * nbn;

  const int rowA = bm * BM;
  const int rowB = bn * BN;

  const int wm = wave >> 1;
  const int wn = wave & 1;

  const unsigned short* aSrc = A + (size_t)(rowA + (tid >> 2)) * K + (tid & 3) * 8;
  const unsigned short* bSrc = B + (size_t)(rowB + (tid >> 2)) * K + (tid & 3) * 8;
  unsigned short* aDst = As + wave * 512;
  unsigned short* bDst = Bs + wave * 512;

  const int lrow = lane & 15;
  const int lko  = (lane >> 4) * 8;

  f32x4 acc[4][4] = {};

  for (int k0 = 0; k0 < K; k0 += BK) {
    GLD_LDS16(aSrc + k0,                  aDst);
    GLD_LDS16(aSrc + k0 + (size_t)64 * K, aDst + 2048);
    GLD_LDS16(bSrc + k0,                  bDst);
    GLD_LDS16(bSrc + k0 + (size_t)64 * K, bDst + 2048);
    __syncthreads();

    f16x8 af[4], bfr[4];
#pragma unroll
    for (int m = 0; m < 4; ++m)
      af[m] = *(const f16x8*)(As + (wm * 64 + m * 16 + lrow) * BK + lko);
#pragma unroll
    for (int n = 0; n < 4; ++n)
      bfr[n] = *(const f16x8*)(Bs + (wn * 64 + n * 16 + lrow) * BK + lko);

#pragma unroll
    for (int m = 0; m < 4; ++m)
#pragma unroll
      for (int n = 0; n < 4; ++n)
        acc[m][n] = __builtin_amdgcn_mfma_f32_16x16x32_f16(af[m], bfr[n], acc[m][n], 0, 0, 0);
    __syncthreads();
  }

  const int ch = lane >> 4;
  const int cl = lane & 15;
#pragma unroll
  for (int n = 0; n < 4; ++n) {
    const int c = rowB + wn * 64 + n * 16 + cl;
    if (c >= Nreal) continue;
    const float bv = bias[c];
#pragma unroll
    for (int m = 0; m < 4; ++m) {
#pragma unroll
      for (int j = 0; j < 4; ++j) {
        const int r = rowA + wm * 64 + m * 16 + ch * 4 + j;
        C[(size_t)r * ldc + c] = acc[m][n][j] + bv;
      }
    }
  }
}

// ---------------- elementwise: binarize fp32 -> bf16 +-1 ----------------
__global__ void k_binarize(const float* __restrict__ in, unsigned short* __restrict__ out, size_t n4) {
  size_t i = (size_t)blockIdx.x * blockDim.x + threadIdx.x;
  const size_t stride = (size_t)gridDim.x * blockDim.x;
  for (; i < n4; i += stride) {
    float4 v = ((const float4*)in)[i];
    us4 o;
    o.x = (v.x >= 0.f) ? 0x3F80 : 0xBF80;
    o.y = (v.y >= 0.f) ? 0x3F80 : 0xBF80;
    o.z = (v.z >= 0.f) ? 0x3F80 : 0xBF80;
    o.w = (v.w >= 0.f) ? 0x3F80 : 0xBF80;
    ((us4*)out)[i] = o;
  }
}

__global__ void k_bnfinal(const double* __restrict__ sums, const float* __restrict__ g,
                          const float* __restrict__ be, float2* __restrict__ coef,
                          int H, double invB) {
  const int j = blockIdx.x * blockDim.x + threadIdx.x;
  if (j >= H) return;
  const double mu  = sums[j] * invB;
  const double var = sums[H + j] * invB - mu * mu;
  const float rstd = (float)(1.0 / sqrt(var + 1e-5));
  const float sc = g[j] * rstd;
  const float sh = be[j] - (float)mu * sc;
  coef[j] = make_float2(sc, sh);
}

// ---------------- BN + sign -> bf16 +-1 (int16 z input) ----------------
__global__ void k_bnsign(const short* __restrict__ Z, const float2* __restrict__ coef,
                         unsigned short* __restrict__ out, size_t n8, int Hmask) {
  size_t i = (size_t)blockIdx.x * blockDim.x + threadIdx.x;
  const size_t stride = (size_t)gridDim.x * blockDim.x;
  for (; i < n8; i += stride) {
    s16x8 z = ((const s16x8*)Z)[i];
    const int c0 = (int)((i << 3) & (size_t)Hmask);
    us8 o;
#pragma unroll
    for (int t = 0; t < 8; ++t) {
      float2 q = coef[c0 + t];
      o[t] = ((float)z[t] * q.x + q.y >= 0.f) ? 0x3F80 : 0xBF80;
    }
    ((us8*)out)[i] = o;
  }
}

// ---------------- BN + clip -> fp16 (int16 z input) ----------------
__global__ void k_bnclip_h(const short* __restrict__ Z, const float2* __restrict__ coef,
                           unsigned short* __restrict__ out, size_t n8, int Hmask) {
  size_t i = (size_t)blockIdx.x * blockDim.x + threadIdx.x;
  const size_t stride = (size_t)gridDim.x * blockDim.x;
  for (; i < n8; i += stride) {
    s16x8 z = ((const s16x8*)Z)[i];
    const int c0 = (int)((i << 3) & (size_t)Hmask);
    us8 o;
#pragma unroll
    for (int t = 0; t < 8; ++t) {
      float2 q = coef[c0 + t];
      float v = (float)z[t] * q.x + q.y;
      v = fminf(1.f, fmaxf(-1.f, v));
      o[t] = f2h_bits(v);
    }
    ((us8*)out)[i] = o;
  }
}

// ---------------- W4 fp32 -> fp16 (padded rows -> zeros) ----------------
__global__ void k_w4h(const float* __restrict__ W4, unsigned short* __restrict__ out,
                      int Nreal, int K, size_t n4) {
  size_t i = (size_t)blockIdx.x * blockDim.x + threadIdx.x;
  const size_t stride = (size_t)gridDim.x * blockDim.x;
  for (; i < n4; i += stride) {
    const size_t e0 = i << 2;
    const int row = (int)(e0 >> 12);  // K = 4096
    us4 o;
    if (row < Nreal) {
      float4 v = ((const float4*)W4)[i];
      o.x = f2h_bits(v.x); o.y = f2h_bits(v.y);
      o.z = f2h_bits(v.z); o.w = f2h_bits(v.w);
    } else {
      o = (us4)0;
    }
    ((us4*)out)[i] = o;
  }
}

// ---------------- launcher ----------------
extern "C" void kernel_launch(void* const* d_in, const int* in_sizes, int n_in,
                              void* d_out, int out_size, void* d_ws, size_t ws_size,
                              hipStream_t stream) {
  (void)in_sizes; (void)n_in; (void)out_size; (void)ws_size;
  const int Bt = 8192, K = 4096, H = 4096, NC = 1000, NCp = 1024;

  const float* x   = (const float*)d_in[0];
  const float* W1  = (const float*)d_in[2];
  const float* g1  = (const float*)d_in[4];
  const float* be1 = (const float*)d_in[5];
  const float* W2  = (const float*)d_in[6];
  const float* g2  = (const float*)d_in[8];
  const float* be2 = (const float*)d_in[9];
  const float* W3  = (const float*)d_in[10];
  const float* g3  = (const float*)d_in[12];
  const float* be3 = (const float*)d_in[13];
  const float* W4  = (const float*)d_in[14];
  const float* b4  = (const float*)d_in[15];
  float* out = (float*)d_out;

  char* ws = (char*)d_ws;
  unsigned short* Ab   = (unsigned short*)(ws);                      // 64MB: activations (bf16 / fp16)
  unsigned short* Wb   = (unsigned short*)(ws + ((size_t)64 << 20)); // 32MB: binarized W; later W4 fp16
  short*          Zs   = (short*)         (ws + ((size_t)96 << 20)); // 64MB: int16 pre-BN z
  double*         sums = (double*)        (ws + ((size_t)288 << 20));
  float2*         coef = (float2*)        (ws + ((size_t)288 << 20) + 2 * H * sizeof(double));

  const dim3 blk(256);
  const size_t nX4 = (size_t)Bt * K / 4;
  const size_t nX8 = (size_t)Bt * K / 8;
  const size_t nW4 = (size_t)H * K / 4;

  k_binarize<<<2048, blk, 0, stream>>>(x, Ab, nX4);

  const float* Ws[3]  = {W1, W2, W3};
  const float* gs[3]  = {g1, g2, g3};
  const float* bes[3] = {be1, be2, be3};

  for (int layer = 0; layer < 3; ++layer) {
    k_binarize<<<2048, blk, 0, stream>>>(Ws[layer], Wb, nW4);
    hipMemsetAsync(sums, 0, 2 * H * sizeof(double), stream);
    gemm256<<<dim3((Bt / 256) * (H / 256)), dim3(512), 0, stream>>>(
        Ab, Wb, Zs, sums, Bt, K, H, H / 256);
    k_bnfinal<<<H / 256, blk, 0, stream>>>(sums, gs[layer], bes[layer], coef, H, 1.0 / Bt);
    if (layer < 2) {
      k_bnsign<<<2048, blk, 0, stream>>>(Zs, coef, Ab, nX8, H - 1);
    } else {
      k_bnclip_h<<<2048, blk, 0, stream>>>(Zs, coef, Ab, nX8, H - 1);  // fp16 act
    }
  }

  // final layer: single fp16 GEMM pass + bias
  k_w4h<<<2048, blk, 0, stream>>>(W4, Wb, NC, K, (size_t)NCp * K / 4);
  gemm_fin_h<<<dim3((Bt / BM) * (NCp / BN)), blk, 0, stream>>>(
      Ab, Wb, out, b4, Bt, K, NC, NC, NCp / BN);
}

// Round 6
// 910.607 us; speedup vs baseline: 2.3566x; 1.3571x over previous
//
#include <hip/hip_runtime.h>
#include <stdint.h>

typedef float f32x4 __attribute__((ext_vector_type(4)));
typedef int   i32x4 __attribute__((ext_vector_type(4)));
typedef _Float16 f16x8 __attribute__((ext_vector_type(8)));
typedef unsigned short us4 __attribute__((ext_vector_type(4)));
typedef unsigned short us8 __attribute__((ext_vector_type(8)));
typedef short s16x8 __attribute__((ext_vector_type(8)));

#define GLD_LDS16(gp, lp) __builtin_amdgcn_global_load_lds( \
    (const __attribute__((address_space(1))) void*)(gp),    \
    (__attribute__((address_space(3))) void*)(lp), 16, 0, 0)

__device__ __forceinline__ unsigned short f2h_bits(float v) {
  union { _Float16 h; unsigned short u; } cv;
  cv.h = (_Float16)v;  // v_cvt_f16_f32, RNE
  return cv.u;
}

// =====================================================================
// 256x256 8-phase i8 GEMM, vmcnt(6) counted pipeline (T1+T2+T3+T4+T5).
// A,B are int8 +-1; BK=128 i8 (same 32KB/tile, same LDS byte layout,
// same swizzle, same staging counts as the round-5 bf16 BK=64 kernel —
// only global row stride, tile count (nt=K/128), and MFMA change).
// Z[M][ldc] (int16, exact integer) ; fused column stats (exact doubles).
// Schedule per iteration (2 K-tiles, 8 phases):
//   P1: buf1.B0<-2i+1   P2: buf0.A0<-2i+2   P3: buf0.B1<-2i+2
//   P4: buf0.A1<-2i+2 +vmcnt(6)             P5: buf0.B0<-2i+2
//   P6: buf1.A0<-2i+3   P7: buf1.B1<-2i+3   P8: buf1.A1<-2i+3 +vmcnt(6)
// =====================================================================

#define READ_A(BUF, MH)                                                        \
  do {                                                                         \
    _Pragma("unroll") for (int mp = 0; mp < 4; ++mp)                           \
      _Pragma("unroll") for (int kk = 0; kk < 2; ++kk)                         \
        a[mp][kk] = *(const i32x4*)(asC + (BUF) * 32768 + (MH) * 16384 +       \
                                    rowOffA[mp] + gsw[kk]);                    \
  } while (0)

#define READ_B(BUF, NH, BREG)                                                  \
  do {                                                                         \
    _Pragma("unroll") for (int np = 0; np < 2; ++np)                           \
      _Pragma("unroll") for (int kk = 0; kk < 2; ++kk)                         \
        BREG[np][kk] = *(const i32x4*)(bsC + (BUF) * 32768 + (NH) * 16384 +    \
                                       rowOffB[np] + gsw[kk]);                 \
  } while (0)

#define STAGE_A(BUF, MH, T)                                                    \
  do {                                                                         \
    int tt = (T); if (tt >= nt) tt -= nt;                                      \
    const size_t ko = (size_t)tt * 128;                                        \
    GLD_LDS16(aStage0 + (size_t)(MH) * 64 * K + ko,                            \
              &As[BUF][(MH) * 8192 + wvOff]);                                  \
    GLD_LDS16(aStage0 + (size_t)(MH) * 64 * K + (size_t)128 * K + ko,          \
              &As[BUF][(MH) * 8192 + 4096 + wvOff]);                           \
  } while (0)

#define STAGE_B(BUF, NH, T)                                                    \
  do {                                                                         \
    int tt = (T); if (tt >= nt) tt -= nt;                                      \
    const size_t ko = (size_t)tt * 128;                                        \
    GLD_LDS16(bStage0 + (size_t)(NH) * 32 * K + ko,                            \
              &Bs[BUF][(NH) * 8192 + wvOff]);                                  \
    GLD_LDS16(bStage0 + (size_t)(NH) * 32 * K + (size_t)128 * K + ko,          \
              &Bs[BUF][(NH) * 8192 + 4096 + wvOff]);                           \
  } while (0)

#define MFMA_Q(MH, NH, BREG)                                                   \
  do {                                                                         \
    _Pragma("unroll") for (int mp = 0; mp < 4; ++mp)                           \
      _Pragma("unroll") for (int np = 0; np < 2; ++np)                         \
        _Pragma("unroll") for (int kk = 0; kk < 2; ++kk)                       \
          acc[(MH) * 4 + mp][(NH) * 2 + np] =                                  \
              __builtin_amdgcn_mfma_i32_16x16x64_i8(                           \
                  a[mp][kk], BREG[np][kk], acc[(MH) * 4 + mp][(NH) * 2 + np],  \
                  0, 0, 0);                                                    \
  } while (0)

#define PH_CORE(MH, NH, BREG, DO_VM)                                           \
  do {                                                                         \
    __builtin_amdgcn_s_barrier();                                              \
    asm volatile("s_waitcnt lgkmcnt(0)" ::: "memory");                         \
    __builtin_amdgcn_sched_barrier(0);                                         \
    __builtin_amdgcn_s_setprio(1);                                             \
    MFMA_Q(MH, NH, BREG);                                                      \
    __builtin_amdgcn_s_setprio(0);                                             \
    if (DO_VM) asm volatile("s_waitcnt vmcnt(6)" ::: "memory");                \
    __builtin_amdgcn_s_barrier();                                              \
    asm volatile("" ::: "memory");                                             \
  } while (0)

__global__ __launch_bounds__(512, 2) void gemm256(
    const uint8_t* __restrict__ A,
    const uint8_t* __restrict__ B,
    short* __restrict__ Z,
    double* __restrict__ sums,
    int M, int K, int ldc, int nbn)
{
  __shared__ unsigned short As[2][16384];  // 32KB per buf (256 x 128 i8)
  __shared__ unsigned short Bs[2][16384];

  const int tid  = threadIdx.x;
  const int wave = tid >> 6;
  const int lane = tid & 63;
  const int wm   = wave >> 2;
  const int wn   = wave & 3;

  const int nwg = gridDim.x;
  const int cpx = nwg >> 3;
  const int bsw = (blockIdx.x & 7) * cpx + (blockIdx.x >> 3);
  const int bm  = bsw / nbn;
  const int bn  = bsw - bm * nbn;
  const int rowA = bm * 256;
  const int rowB = bn * 256;

  const int nt = K >> 7;  // K-tiles of 128 i8

  // staging addresses (pre-swizzled global source, linear LDS dest).
  // row = 128B = 8 granules of 16B; granule' = granule ^ (row&7).
  const int trow = tid >> 3;
  const int gl   = (tid & 7) ^ (trow & 7);
  const uint8_t* aStage0 = A + (size_t)(rowA + trow) * K + gl * 16;
  const uint8_t* bStage0 =
      B + (size_t)(rowB + ((trow >> 5) << 6) + (trow & 31)) * K + gl * 16;
  const int wvOff = wave * 512;  // ushort units = 1024B

  // read addresses (swizzled) — byte-identical to the bf16 BK=64 kernel
  const char* asC = (const char*)&As[0][0];
  const char* bsC = (const char*)&Bs[0][0];
  int rowOffA[4], rowOffB[2], gsw[2];
#pragma unroll
  for (int mp = 0; mp < 4; ++mp)
    rowOffA[mp] = (wm * 64 + mp * 16 + (lane & 15)) * 128;
#pragma unroll
  for (int np = 0; np < 2; ++np)
    rowOffB[np] = (wn * 32 + np * 16 + (lane & 15)) * 128;
#pragma unroll
  for (int kk = 0; kk < 2; ++kk)
    gsw[kk] = ((((kk << 2) | (lane >> 4)) ^ (lane & 7)) << 4);

  i32x4 a[4][2], bb0[2][2], bb1[2][2];
  i32x4 acc[8][4] = {};

  // prologue: buf0 <- t0 (A0,B1,A1,B0), buf1 <- t1 (A0,B1,A1)
  STAGE_A(0, 0, 0); STAGE_B(0, 1, 0); STAGE_A(0, 1, 0); STAGE_B(0, 0, 0);
  STAGE_A(1, 0, 1); STAGE_B(1, 1, 1); STAGE_A(1, 1, 1);
  asm volatile("s_waitcnt vmcnt(6)" ::: "memory");
  __builtin_amdgcn_s_barrier();
  asm volatile("" ::: "memory");

  const int ni = nt >> 1;
  for (int i = 0; i < ni; ++i) {
    const int tb0 = 2 * i + 2, tb1 = 2 * i + 3;
    // P1 (buf0, M0, N0)
    READ_A(0, 0); READ_B(0, 0, bb0);
    STAGE_B(1, 0, 2 * i + 1);
    PH_CORE(0, 0, bb0, 0);
    // P2 (buf0, M0, N1)
    READ_B(0, 1, bb1);
    STAGE_A(0, 0, tb0);
    PH_CORE(0, 1, bb1, 0);
    // P3 (buf0, M1, N1)
    READ_A(0, 1);
    STAGE_B(0, 1, tb0);
    PH_CORE(1, 1, bb1, 0);
    // P4 (buf0, M1, N0) — no reads
    STAGE_A(0, 1, tb0);
    PH_CORE(1, 0, bb0, 1);
    // P5 (buf1, M0, N0)
    READ_A(1, 0); READ_B(1, 0, bb0);
    STAGE_B(0, 0, tb0);
    PH_CORE(0, 0, bb0, 0);
    // P6 (buf1, M0, N1)
    READ_B(1, 1, bb1);
    STAGE_A(1, 0, tb1);
    PH_CORE(0, 1, bb1, 0);
    // P7 (buf1, M1, N1)
    READ_A(1, 1);
    STAGE_B(1, 1, tb1);
    PH_CORE(1, 1, bb1, 0);
    // P8 (buf1, M1, N0) — no reads
    STAGE_A(1, 1, tb1);
    PH_CORE(1, 0, bb0, 1);
  }

  // epilogue: fused column stats (exact: z is integer) + int16 Z store.
  // D layout: col = lane&15, row = (lane>>4)*4 + j (dtype-independent)
  const int cl  = lane & 15;
  const int ch4 = (lane >> 4) * 4;
#pragma unroll
  for (int nh = 0; nh < 2; ++nh) {
#pragma unroll
    for (int np = 0; np < 2; ++np) {
      const int c = rowB + wn * 64 + nh * 32 + np * 16 + cl;
      double s = 0.0, ss = 0.0;
#pragma unroll
      for (int mh = 0; mh < 2; ++mh) {
#pragma unroll
        for (int mp = 0; mp < 4; ++mp) {
#pragma unroll
          for (int j = 0; j < 4; ++j) {
            const double d = (double)acc[mh * 4 + mp][nh * 2 + np][j];
            s += d; ss += d * d;
          }
        }
      }
      s  += __shfl_xor(s, 16);  s  += __shfl_xor(s, 32);
      ss += __shfl_xor(ss, 16); ss += __shfl_xor(ss, 32);
      if (lane < 16) {
        unsafeAtomicAdd(&sums[c], s);
        unsafeAtomicAdd(&sums[ldc + c], ss);
      }
#pragma unroll
      for (int mh = 0; mh < 2; ++mh) {
#pragma unroll
        for (int mp = 0; mp < 4; ++mp) {
          const int r = rowA + wm * 128 + mh * 64 + mp * 16 + ch4;
          short* p = Z + (size_t)r * ldc + c;
#pragma unroll
          for (int j = 0; j < 4; ++j)
            p[(size_t)j * ldc] = (short)acc[mh * 4 + mp][nh * 2 + np][j];
        }
      }
    }
  }
}

// =====================================================================
// Final layer, single fp16 pass: C = Ah*Bh^T + bias, fp32 out.
// 128x128 m97 structure (unchanged from round 5).
// =====================================================================
#define BM 128
#define BN 128
#define BK 32

__global__ __launch_bounds__(256) void gemm_fin_h(
    const unsigned short* __restrict__ A,   // fp16 bits [M][K]
    const unsigned short* __restrict__ B,   // fp16 bits [1024][K]
    float* __restrict__ C, const float* __restrict__ bias,
    int M, int K, int ldc, int Nreal, int nbn)
{
  __shared__ unsigned short As[BM * BK];
  __shared__ unsigned short Bs[BN * BK];

  const int tid  = threadIdx.x;
  const int wave = tid >> 6;
  const int lane = tid & 63;

  const int nwg = gridDim.x;
  const int cpx = nwg >> 3;
  const int b   = blockIdx.x;
  const int swz = (b & 7) * cpx + (b >> 3);
  const int bm  = swz / nbn;
  const int bn  = swz - bm * nbn;

  const int rowA = bm * BM;
  const int rowB = bn * BN;

  const int wm = wave >> 1;
  const int wn = wave & 1;

  const unsigned short* aSrc = A + (size_t)(rowA + (tid >> 2)) * K + (tid & 3) * 8;
  const unsigned short* bSrc = B + (size_t)(rowB + (tid >> 2)) * K + (tid & 3) * 8;
  unsigned short* aDst = As + wave * 512;
  unsigned short* bDst = Bs + wave * 512;

  const int lrow = lane & 15;
  const int lko  = (lane >> 4) * 8;

  f32x4 acc[4][4] = {};

  for (int k0 = 0; k0 < K; k0 += BK) {
    GLD_LDS16(aSrc + k0,                  aDst);
    GLD_LDS16(aSrc + k0 + (size_t)64 * K, aDst + 2048);
    GLD_LDS16(bSrc + k0,                  bDst);
    GLD_LDS16(bSrc + k0 + (size_t)64 * K, bDst + 2048);
    __syncthreads();

    f16x8 af[4], bfr[4];
#pragma unroll
    for (int m = 0; m < 4; ++m)
      af[m] = *(const f16x8*)(As + (wm * 64 + m * 16 + lrow) * BK + lko);
#pragma unroll
    for (int n = 0; n < 4; ++n)
      bfr[n] = *(const f16x8*)(Bs + (wn * 64 + n * 16 + lrow) * BK + lko);

#pragma unroll
    for (int m = 0; m < 4; ++m)
#pragma unroll
      for (int n = 0; n < 4; ++n)
        acc[m][n] = __builtin_amdgcn_mfma_f32_16x16x32_f16(af[m], bfr[n], acc[m][n], 0, 0, 0);
    __syncthreads();
  }

  const int ch = lane >> 4;
  const int cl = lane & 15;
#pragma unroll
  for (int n = 0; n < 4; ++n) {
    const int c = rowB + wn * 64 + n * 16 + cl;
    if (c >= Nreal) continue;
    const float bv = bias[c];
#pragma unroll
    for (int m = 0; m < 4; ++m) {
#pragma unroll
      for (int j = 0; j < 4; ++j) {
        const int r = rowA + wm * 64 + m * 16 + ch * 4 + j;
        C[(size_t)r * ldc + c] = acc[m][n][j] + bv;
      }
    }
  }
}

// ---------------- binarize fp32 -> i8 +-1 (4 per u32) ----------------
__global__ void k_binarize8(const float* __restrict__ in, uint32_t* __restrict__ out, size_t n4) {
  size_t i = (size_t)blockIdx.x * blockDim.x + threadIdx.x;
  const size_t stride = (size_t)gridDim.x * blockDim.x;
  for (; i < n4; i += stride) {
    float4 v = ((const float4*)in)[i];
    uint32_t o = (v.x >= 0.f ? 0x01u : 0xFFu)
               | ((v.y >= 0.f ? 0x01u : 0xFFu) << 8)
               | ((v.z >= 0.f ? 0x01u : 0xFFu) << 16)
               | ((v.w >= 0.f ? 0x01u : 0xFFu) << 24);
    out[i] = o;
  }
}

__global__ void k_bnfinal(const double* __restrict__ sums, const float* __restrict__ g,
                          const float* __restrict__ be, float2* __restrict__ coef,
                          int H, double invB) {
  const int j = blockIdx.x * blockDim.x + threadIdx.x;
  if (j >= H) return;
  const double mu  = sums[j] * invB;
  const double var = sums[H + j] * invB - mu * mu;
  const float rstd = (float)(1.0 / sqrt(var + 1e-5));
  const float sc = g[j] * rstd;
  const float sh = be[j] - (float)mu * sc;
  coef[j] = make_float2(sc, sh);
}

// ---------------- BN + sign -> i8 +-1 (int16 z input) ----------------
__global__ void k_bnsign8(const short* __restrict__ Z, const float2* __restrict__ coef,
                          unsigned long long* __restrict__ out, size_t n8, int Hmask) {
  size_t i = (size_t)blockIdx.x * blockDim.x + threadIdx.x;
  const size_t stride = (size_t)gridDim.x * blockDim.x;
  for (; i < n8; i += stride) {
    s16x8 z = ((const s16x8*)Z)[i];
    const int c0 = (int)((i << 3) & (size_t)Hmask);
    unsigned long long o = 0;
#pragma unroll
    for (int t = 0; t < 8; ++t) {
      float2 q = coef[c0 + t];
      unsigned long long b = ((float)z[t] * q.x + q.y >= 0.f) ? 0x01ull : 0xFFull;
      o |= b << (8 * t);
    }
    out[i] = o;
  }
}

// ---------------- BN + clip -> fp16 (int16 z input) ----------------
__global__ void k_bnclip_h(const short* __restrict__ Z, const float2* __restrict__ coef,
                           unsigned short* __restrict__ out, size_t n8, int Hmask) {
  size_t i = (size_t)blockIdx.x * blockDim.x + threadIdx.x;
  const size_t stride = (size_t)gridDim.x * blockDim.x;
  for (; i < n8; i += stride) {
    s16x8 z = ((const s16x8*)Z)[i];
    const int c0 = (int)((i << 3) & (size_t)Hmask);
    us8 o;
#pragma unroll
    for (int t = 0; t < 8; ++t) {
      float2 q = coef[c0 + t];
      float v = (float)z[t] * q.x + q.y;
      v = fminf(1.f, fmaxf(-1.f, v));
      o[t] = f2h_bits(v);
    }
    ((us8*)out)[i] = o;
  }
}

// ---------------- W4 fp32 -> fp16 (padded rows -> zeros) ----------------
__global__ void k_w4h(const float* __restrict__ W4, unsigned short* __restrict__ out,
                      int Nreal, int K, size_t n4) {
  size_t i = (size_t)blockIdx.x * blockDim.x + threadIdx.x;
  const size_t stride = (size_t)gridDim.x * blockDim.x;
  for (; i < n4; i += stride) {
    const size_t e0 = i << 2;
    const int row = (int)(e0 >> 12);  // K = 4096
    us4 o;
    if (row < Nreal) {
      float4 v = ((const float4*)W4)[i];
      o.x = f2h_bits(v.x); o.y = f2h_bits(v.y);
      o.z = f2h_bits(v.z); o.w = f2h_bits(v.w);
    } else {
      o = (us4)0;
    }
    ((us4*)out)[i] = o;
  }
}

// ---------------- launcher ----------------
extern "C" void kernel_launch(void* const* d_in, const int* in_sizes, int n_in,
                              void* d_out, int out_size, void* d_ws, size_t ws_size,
                              hipStream_t stream) {
  (void)in_sizes; (void)n_in; (void)out_size; (void)ws_size;
  const int Bt = 8192, K = 4096, H = 4096, NC = 1000, NCp = 1024;

  const float* x   = (const float*)d_in[0];
  const float* W1  = (const float*)d_in[2];
  const float* g1  = (const float*)d_in[4];
  const float* be1 = (const float*)d_in[5];
  const float* W2  = (const float*)d_in[6];
  const float* g2  = (const float*)d_in[8];
  const float* be2 = (const float*)d_in[9];
  const float* W3  = (const float*)d_in[10];
  const float* g3  = (const float*)d_in[12];
  const float* be3 = (const float*)d_in[13];
  const float* W4  = (const float*)d_in[14];
  const float* b4  = (const float*)d_in[15];
  float* out = (float*)d_out;

  char* ws = (char*)d_ws;
  uint8_t*        Ab8  = (uint8_t*)(ws);                             // 32MB: i8 acts (region reserves 64MB for fp16 layer-3 acts)
  unsigned short* Abh  = (unsigned short*)(ws);                      // fp16 acts (layer 3), same region
  uint8_t*        Wb8  = (uint8_t*)(ws + ((size_t)64 << 20));        // 16MB: i8 weights / fp16 W4 (8MB)
  unsigned short* W4h  = (unsigned short*)(ws + ((size_t)64 << 20));
  short*          Zs   = (short*)(ws + ((size_t)96 << 20));          // 64MB: int16 pre-BN z
  double*         sums = (double*)(ws + ((size_t)288 << 20));
  float2*         coef = (float2*)(ws + ((size_t)288 << 20) + 2 * H * sizeof(double));

  const dim3 blk(256);
  const size_t nX4 = (size_t)Bt * K / 4;  // float4 groups (x)
  const size_t nX8 = (size_t)Bt * K / 8;  // s16x8 groups (Z)
  const size_t nW4 = (size_t)H * K / 4;

  k_binarize8<<<2048, blk, 0, stream>>>(x, (uint32_t*)Ab8, nX4);

  const float* Ws[3]  = {W1, W2, W3};
  const float* gs[3]  = {g1, g2, g3};
  const float* bes[3] = {be1, be2, be3};

  for (int layer = 0; layer < 3; ++layer) {
    k_binarize8<<<2048, blk, 0, stream>>>(Ws[layer], (uint32_t*)Wb8, nW4);
    hipMemsetAsync(sums, 0, 2 * H * sizeof(double), stream);
    gemm256<<<dim3((Bt / 256) * (H / 256)), dim3(512), 0, stream>>>(
        Ab8, Wb8, Zs, sums, Bt, K, H, H / 256);
    k_bnfinal<<<H / 256, blk, 0, stream>>>(sums, gs[layer], bes[layer], coef, H, 1.0 / Bt);
    if (layer < 2) {
      k_bnsign8<<<2048, blk, 0, stream>>>(Zs, coef, (unsigned long long*)Ab8, nX8, H - 1);
    } else {
      k_bnclip_h<<<2048, blk, 0, stream>>>(Zs, coef, Abh, nX8, H - 1);  // fp16 act
    }
  }

  // final layer: single fp16 GEMM pass + bias
  k_w4h<<<2048, blk, 0, stream>>>(W4, W4h, NC, K, (size_t)NCp * K / 4);
  gemm_fin_h<<<dim3((Bt / BM) * (NCp / BN)), blk, 0, stream>>>(
      Abh, W4h, out, b4, Bt, K, NC, NC, NCp / BN);
}